// Round 5
// baseline (905.916 us; speedup 1.0000x reference)
//
#include <hip/hip_runtime.h>
#include <hip/hip_cooperative_groups.h>

namespace cg = cooperative_groups;

// Problem constants (from reference)
#define Nn 1024
#define Hh 96
#define Ee 16384
#define IN_K 9       // IN_RAW-1
#define IN_STRIDE 10 // x is (N, 10), we use first 9 cols
#define NH (Nn * Hh)
#define XS 128       // padded row stride for x-like (N,96) buffers
#define KSLICES 8
#define SLICE 128    // 1024 / KSLICES
#define TPB 256
#define MAXGRID 1024

__device__ __forceinline__ float sigf(float v) {
    return __builtin_amdgcn_rcpf(1.0f + __expf(-v));
}
__device__ __forceinline__ float tanhfast(float v) {
    float e = __expf(2.0f * v);
    return (e - 1.0f) * __builtin_amdgcn_rcpf(e + 1.0f);
}
__device__ __forceinline__ float leakyf(float v) {
    return v >= 0.0f ? v : 0.01f * v;
}

struct Params {
    const float* x_in; const int* ei; const int* adj;
    const float* W_init; const float* b_init; const float* W_ggc;
    const float* W_ih; const float* W_hh; const float* b_ih; const float* b_hh;
    const float* Wa1; const float* ba1; const float* Wa2; const float* ba2;
    const float* Wo1; const float* bo1; const float* Wo2; const float* bo2;
    const float* Wp1; const float* bp1; const float* Wp2; const float* bp2;
    float* out;
    // workspace
    float* xA; float* xB; float* Ei; float* EjT; float* cnt;
    float* partial; float* A_edge;
    float* Wt_ih; float* Wt_hh; float* Wf;
    float* Wt_a1i; float* Wt_a1j; float* Wt_o1; float* Wt_o2;
};

// Single cooperative kernel: all phases separated by grid.sync().
// Phases (virtual-block grid-stride so any resident grid size works):
//  0: weight transposes + zero A_edge/cnt + init linear
//  1: edge-matrix build (atomics) + Wf = W_ggc @ W_ih.T fold
//  per unroll (x2):
//  2: split-k GEMM partial = A_edge @ xA    (also C @ xB reuses this? no - C stays in LDS)
//  3: GRU fused (reduce partials -> P in LDS, GRU cell, attn projections, exps)
//  4: coeffs row (dense masked, C-row in LDS) + row-GEMM -> new xA
//  5: output head (row-local lin1+lin2+heads)
__global__ __launch_bounds__(TPB, 4) void mega_kernel(Params p)
{
    cg::grid_group grid = cg::this_grid();
    __shared__ float sm[1408];   // 5.6 KB phase-union scratch
    const int tid = threadIdx.x;
    const int nb = gridDim.x;

    // ---------------- phase 0: setup ----------------
    for (int gt = blockIdx.x * TPB + tid; gt < 262144; gt += nb * TPB) {
        // zero A_edge (1M floats as 256K float4)
        ((float4*)p.A_edge)[gt] = make_float4(0.f, 0.f, 0.f, 0.f);
        if (gt < Nn) p.cnt[gt] = 0.0f;
        // weight transposes (92160 elements total)
        if (gt < 92160) {
            int idx = gt;
            if (idx < 27648) {
                int k = idx / 288, c = idx % 288;
                p.Wt_ih[idx] = p.W_ih[c * 96 + k];
            } else if ((idx -= 27648) < 27648) {
                int k = idx / 288, c = idx % 288;
                p.Wt_hh[idx] = p.W_hh[c * 96 + k];
            } else if ((idx -= 27648) < 9216) {
                int k = idx / 96, h = idx % 96;
                p.Wt_a1i[idx] = p.Wa1[h * 192 + k];
            } else if ((idx -= 9216) < 9216) {
                int k = idx / 96, h = idx % 96;
                p.Wt_a1j[idx] = p.Wa1[h * 192 + 96 + k];
            } else if ((idx -= 9216) < 9216) {
                int k = idx / 96, j = idx % 96;
                p.Wt_o1[idx] = p.Wo1[j * 96 + k];
            } else {
                idx -= 9216;
                int k = idx / 96, j = idx % 96;
                p.Wt_o2[idx] = p.Wo2[j * 96 + k];
            }
        }
        // init linear: xA[n*XS+j] = leaky(x[n,:9] @ W_init[j,:] + b_init[j])
        if (gt < NH) {
            int n = gt / Hh, j = gt - n * Hh;
            const float* xr = p.x_in + n * IN_STRIDE;
            const float* wr = p.W_init + j * IN_K;
            float acc = p.b_init[j];
#pragma unroll
            for (int k = 0; k < IN_K; ++k) acc += xr[k] * wr[k];
            p.xA[n * XS + j] = leakyf(acc);
        }
    }
    grid.sync();

    // ---------------- phase 1: edges + Wf ----------------
    for (int gt = blockIdx.x * TPB + tid; gt < Ee + 27648; gt += nb * TPB) {
        if (gt < Ee) {
            int src = p.ei[gt];
            int tgt = p.ei[Ee + gt];
            atomicAdd(&p.A_edge[tgt * Nn + src], 1.0f);
            atomicAdd(&p.cnt[tgt], 1.0f);
        } else {
            int idx = gt - Ee;            // Wf[k][c] = sum_j W_ggc[k][j]*W_ih[c][j]
            int k = idx / 288, c = idx % 288;
            const float* g = p.W_ggc + k * 96;
            const float* w = p.Wt_ih + c;
            float acc = 0.0f;
            for (int j = 0; j < 96; ++j) acc += g[j] * w[j * 288];
            p.Wf[idx] = acc;
        }
    }
    grid.sync();

    for (int u = 0; u < 2; ++u) {
        // ------------- phase 2: split-k GEMM partial = A_edge @ xA -------------
        for (int vb = blockIdx.x; vb < 128 * KSLICES; vb += nb) {
            int tile = vb & 127;
            int s = vb >> 7;
            int hg = tid & 31;
            int nl = tid >> 5;
            int n = tile * 8 + nl;
            int k0 = s * SLICE;
            int h4 = hg * 4;
            const float* arow = p.A_edge + n * Nn + k0;
            const float* xp = p.xA + k0 * XS + h4;
            float4 acc = make_float4(0.f, 0.f, 0.f, 0.f);
#pragma unroll 4
            for (int kk = 0; kk < SLICE; kk += 4) {
                float4 a4 = *(const float4*)(arow + kk);
                float4 x0 = *(const float4*)(xp + (kk + 0) * XS);
                float4 x1 = *(const float4*)(xp + (kk + 1) * XS);
                float4 x2 = *(const float4*)(xp + (kk + 2) * XS);
                float4 x3 = *(const float4*)(xp + (kk + 3) * XS);
                acc.x += a4.x * x0.x; acc.y += a4.x * x0.y; acc.z += a4.x * x0.z; acc.w += a4.x * x0.w;
                acc.x += a4.y * x1.x; acc.y += a4.y * x1.y; acc.z += a4.y * x1.z; acc.w += a4.y * x1.w;
                acc.x += a4.z * x2.x; acc.y += a4.z * x2.y; acc.z += a4.z * x2.z; acc.w += a4.z * x2.w;
                acc.x += a4.w * x3.x; acc.y += a4.w * x3.y; acc.z += a4.w * x3.z; acc.w += a4.w * x3.w;
            }
            *(float4*)(p.partial + (s * Nn + n) * XS + h4) = acc;
        }
        grid.sync();

        // ------------- phase 3: GRU fused (2 rows per vblock) -------------
        // sm layout: Prow[2][96] @0, xrow[2][96] @192, xout[2][96] @384
        for (int vb = blockIdx.x; vb < Nn / 2; vb += nb) {
            int r = tid >> 7;          // 0..1
            int h = tid & 127;
            int n = vb * 2 + r;
            bool act = h < Hh;
            if (act) {
                float acc = 0.0f;
#pragma unroll
                for (int s = 0; s < KSLICES; ++s)
                    acc += p.partial[(s * Nn + n) * XS + h];
                float inv = __builtin_amdgcn_rcpf(fmaxf(p.cnt[n], 1.0f));
                sm[r * 96 + h] = acc * inv;          // Prow
                sm[192 + r * 96 + h] = p.xA[n * XS + h];   // xrow
            }
            __syncthreads();
            if (act) {
                const float* Pr = sm + r * 96;
                const float* xr = sm + 192 + r * 96;
                const float* pf = p.Wf + h;
                const float* ph = p.Wt_hh + h;
                float gir = p.b_ih[h], giz = p.b_ih[Hh + h], gin = p.b_ih[2 * Hh + h];
                float ghr = p.b_hh[h], ghz = p.b_hh[Hh + h], ghn = p.b_hh[2 * Hh + h];
                for (int k = 0; k < Hh; ++k) {
                    float a = Pr[k];
                    float xv = xr[k];
                    int o = k * 288;
                    gir += a * pf[o];
                    giz += a * pf[o + 96];
                    gin += a * pf[o + 192];
                    ghr += xv * ph[o];
                    ghz += xv * ph[o + 96];
                    ghn += xv * ph[o + 192];
                }
                float rr = sigf(gir + ghr);
                float z = sigf(giz + ghz);
                float nn2 = tanhfast(gin + rr * ghn);
                float xo = (1.0f - z) * nn2 + z * xr[h];
                p.xB[n * XS + h] = xo;
                sm[384 + r * 96 + h] = xo;
            }
            __syncthreads();
            if (act) {
                const float* row = sm + 384 + r * 96;
                const float* wi = p.Wt_a1i + h;
                const float* wj = p.Wt_a1j + h;
                float a = 0.0f, bb = 0.0f;
                for (int k = 0; k < Hh; ++k) {
                    float xv = row[k];
                    a += xv * wi[k * 96];
                    bb += xv * wj[k * 96];
                }
                p.Ei[n * Hh + h] = __expf(-(a + p.ba1[h]));
                p.EjT[h * Nn + n] = __expf(-bb);
            }
            __syncthreads();
        }
        grid.sync();

        // ------------- phase 4: coeffs row + row-GEMM -> xA -------------
        // sm: Crow[1024] @0, eis[96] @1024, wsv[96] @1120, part[96] @1216
        for (int i = blockIdx.x; i < Nn; i += nb) {
            if (tid < Hh) {
                sm[1024 + tid] = p.Ei[i * Hh + tid];
                sm[1120 + tid] = p.Wa2[tid];
            }
            __syncthreads();
            {
                int j0 = tid * 4;
                float s0 = 0.f, s1 = 0.f, s2 = 0.f, s3 = 0.f;
#pragma unroll 4
                for (int k = 0; k < Hh; ++k) {
                    float4 e4 = *(const float4*)(p.EjT + k * Nn + j0);
                    float eik = sm[1024 + k];
                    float wk = sm[1120 + k];
                    s0 += __builtin_amdgcn_rcpf(fmaf(eik, e4.x, 1.0f)) * wk;
                    s1 += __builtin_amdgcn_rcpf(fmaf(eik, e4.y, 1.0f)) * wk;
                    s2 += __builtin_amdgcn_rcpf(fmaf(eik, e4.z, 1.0f)) * wk;
                    s3 += __builtin_amdgcn_rcpf(fmaf(eik, e4.w, 1.0f)) * wk;
                }
                float b2 = p.ba2[0];
                int4 mk = *(const int4*)(p.adj + i * Nn + j0);
                float4 c;
                c.x = (mk.x == 1) ? sigf(s0 + b2) : 0.0f;
                c.y = (mk.y == 1) ? sigf(s1 + b2) : 0.0f;
                c.z = (mk.z == 1) ? sigf(s2 + b2) : 0.0f;
                c.w = (mk.w == 1) ? sigf(s3 + b2) : 0.0f;
                *(float4*)(sm + j0) = c;   // C row stays in LDS
            }
            __syncthreads();
            {
                int c2 = tid >> 7;         // 0,1 j-halves
                int h = tid & 127;
                float acc = 0.0f;
                if (h < Hh) {
                    const float* xc = p.xB + h;
                    int jb = c2 * 512;
                    for (int j = 0; j < 512; ++j)
                        acc += sm[jb + j] * xc[(jb + j) * XS];
                    if (c2) sm[1216 + h] = acc;
                }
                __syncthreads();
                if (c2 == 0 && h < Hh)
                    p.xA[i * XS + h] = acc + sm[1216 + h];
            }
            __syncthreads();
        }
        grid.sync();
    }

    // ---------------- phase 5: head (row-local) ----------------
    // sm: xrow[96] @0, t1[96] @96, t2[96] @192, p1[96] @288, p2[96] @384
    for (int i = blockIdx.x; i < Nn; i += nb) {
        if (tid < Hh) sm[tid] = p.xA[i * XS + tid];
        __syncthreads();
        if (tid < Hh) {
            const float* w = p.Wt_o1 + tid;
            float acc = p.bo1[tid];
            for (int k = 0; k < Hh; ++k) acc += sm[k] * w[k * 96];
            sm[96 + tid] = leakyf(acc);
        }
        __syncthreads();
        if (tid < Hh) {
            const float* w = p.Wt_o2 + tid;
            float acc = p.bo2[tid];
            for (int k = 0; k < Hh; ++k) acc += sm[96 + k] * w[k * 96];
            sm[192 + tid] = leakyf(acc);
        }
        __syncthreads();
        if (tid < Hh) {
            sm[288 + tid] = sm[192 + tid] * p.Wp1[tid];
            sm[384 + tid] = sm[192 + tid] * p.Wp2[tid];
        }
        __syncthreads();
        if (tid == 0) {
            float s1 = 0.f, s2 = 0.f;
            for (int k = 0; k < Hh; ++k) { s1 += sm[288 + k]; s2 += sm[384 + k]; }
            p.out[i] = sigf(s1 + p.bp1[0]);
            p.out[Nn + i] = sigf(s2 + p.bp2[0]);
        }
        __syncthreads();
    }
}

extern "C" void kernel_launch(void* const* d_in, const int* in_sizes, int n_in,
                              void* d_out, int out_size, void* d_ws, size_t ws_size,
                              hipStream_t stream)
{
    Params p;
    p.x_in   = (const float*)d_in[0];
    p.ei     = (const int*)d_in[1];
    p.adj    = (const int*)d_in[2];
    p.W_init = (const float*)d_in[3];
    p.b_init = (const float*)d_in[4];
    p.W_ggc  = (const float*)d_in[5];
    p.W_ih   = (const float*)d_in[6];
    p.W_hh   = (const float*)d_in[7];
    p.b_ih   = (const float*)d_in[8];
    p.b_hh   = (const float*)d_in[9];
    p.Wa1    = (const float*)d_in[10];
    p.ba1    = (const float*)d_in[11];
    p.Wa2    = (const float*)d_in[12];
    p.ba2    = (const float*)d_in[13];
    p.Wo1    = (const float*)d_in[14];
    p.bo1    = (const float*)d_in[15];
    p.Wo2    = (const float*)d_in[16];
    p.bo2    = (const float*)d_in[17];
    p.Wp1    = (const float*)d_in[18];
    p.bp1    = (const float*)d_in[19];
    p.Wp2    = (const float*)d_in[20];
    p.bp2    = (const float*)d_in[21];
    p.out    = (float*)d_out;

    float* ws = (float*)d_ws;
    p.xA      = ws;                         // (N, XS)
    p.xB      = p.xA + Nn * XS;             // (N, XS)
    p.Ei      = p.xB + Nn * XS;             // (N, 96)
    p.EjT     = p.Ei + NH;                  // (96, N)
    p.cnt     = p.EjT + NH;                 // (N)
    p.partial = p.cnt + Nn;                 // (KSLICES, N, XS) = 4 MB
    p.A_edge  = p.partial + KSLICES * Nn * XS;  // (N, N)
    p.Wt_ih   = p.A_edge + Nn * Nn;         // 96*288
    p.Wt_hh   = p.Wt_ih + 27648;
    p.Wf      = p.Wt_hh + 27648;
    p.Wt_a1i  = p.Wf + 27648;
    p.Wt_a1j  = p.Wt_a1i + 9216;
    p.Wt_o1   = p.Wt_a1j + 9216;
    p.Wt_o2   = p.Wt_o1 + 9216;

    // Clamp grid to what can be co-resident (cooperative launch requirement).
    int maxPerCU = 0;
    hipOccupancyMaxActiveBlocksPerMultiprocessor(&maxPerCU, mega_kernel, TPB, 0);
    if (maxPerCU < 1) maxPerCU = 1;
    int grid = maxPerCU * 256;              // 256 CUs on MI355X
    if (grid > MAXGRID) grid = MAXGRID;

    void* args[] = { &p };
    hipLaunchCooperativeKernel((const void*)mega_kernel, dim3(grid), dim3(TPB),
                               args, 0, stream);
}

// Round 6
// 227.814 us; speedup vs baseline: 3.9766x; 3.9766x over previous
//
#include <hip/hip_runtime.h>

// Problem constants (from reference)
#define Nn 1024
#define Hh 96
#define Ee 16384
#define IN_K 9       // IN_RAW-1
#define IN_STRIDE 10 // x is (N, 10), we use first 9 cols
#define NH (Nn * Hh)
#define XS 128       // padded row stride for x-like (N,96) buffers
#define SLOTS 64     // CSR bucket capacity (Poisson(16) degree; P(>64) ~ 0)

__device__ __forceinline__ float sigf(float v) {
    return __builtin_amdgcn_rcpf(1.0f + __expf(-v));
}
__device__ __forceinline__ float tanhfast(float v) {
    float e = __expf(2.0f * v);
    return (e - 1.0f) * __builtin_amdgcn_rcpf(e + 1.0f);
}
__device__ __forceinline__ float leakyf(float v) {
    return v >= 0.0f ? v : 0.01f * v;
}

// ---------------- setup1: weight transposes + zero degree + init linear ----
__global__ __launch_bounds__(256) void setup1_kernel(
    const float* __restrict__ W_ih, const float* __restrict__ W_hh,
    const float* __restrict__ Wa1, const float* __restrict__ Wo1,
    const float* __restrict__ Wo2, const float* __restrict__ x_in,
    const float* __restrict__ W_init, const float* __restrict__ b_init,
    float* __restrict__ Wt_ih, float* __restrict__ Wt_hh,
    float* __restrict__ Wt_a1i, float* __restrict__ Wt_a1j,
    float* __restrict__ Wt_o1, float* __restrict__ Wt_o2,
    int* __restrict__ deg, float* __restrict__ xA)
{
    int gt = blockIdx.x * 256 + threadIdx.x;
    if (gt < Nn) deg[gt] = 0;
    if (gt < 92160) {
        int idx = gt;
        if (idx < 27648) {
            int k = idx / 288, c = idx % 288;
            Wt_ih[idx] = W_ih[c * 96 + k];
        } else if ((idx -= 27648) < 27648) {
            int k = idx / 288, c = idx % 288;
            Wt_hh[idx] = W_hh[c * 96 + k];
        } else if ((idx -= 27648) < 9216) {
            int k = idx / 96, h = idx % 96;
            Wt_a1i[idx] = Wa1[h * 192 + k];
        } else if ((idx -= 9216) < 9216) {
            int k = idx / 96, h = idx % 96;
            Wt_a1j[idx] = Wa1[h * 192 + 96 + k];
        } else if ((idx -= 9216) < 9216) {
            int k = idx / 96, j = idx % 96;
            Wt_o1[idx] = Wo1[j * 96 + k];
        } else {
            idx -= 9216;
            int k = idx / 96, j = idx % 96;
            Wt_o2[idx] = Wo2[j * 96 + k];
        }
    }
    if (gt < NH) {
        int n = gt / Hh, j = gt - n * Hh;
        const float* xr = x_in + n * IN_STRIDE;
        const float* wr = W_init + j * IN_K;
        float acc = b_init[j];
#pragma unroll
        for (int k = 0; k < IN_K; ++k) acc += xr[k] * wr[k];
        xA[n * XS + j] = leakyf(acc);
    }
}

// ---------------- setup2: CSR bucket scatter + Wf = W_ggc @ W_ih.T ---------
__global__ __launch_bounds__(256) void setup2_kernel(
    const int* __restrict__ ei, const float* __restrict__ W_ggc,
    const float* __restrict__ Wt_ih,
    int* __restrict__ deg, int* __restrict__ bucket, float* __restrict__ Wf)
{
    int gt = blockIdx.x * 256 + threadIdx.x;
    if (gt < Ee) {
        int src = ei[gt];
        int tgt = ei[Ee + gt];
        int slot = atomicAdd(&deg[tgt], 1);
        if (slot < SLOTS) bucket[tgt * SLOTS + slot] = src;
    } else if (gt < Ee + 27648) {
        int idx = gt - Ee;   // Wf[k][c] = sum_j W_ggc[k][j] * W_ih[c][j]
        int k = idx / 288, c = idx % 288;
        const float* g = W_ggc + k * 96;
        const float* w = Wt_ih + c;
        float acc = 0.0f;
        for (int j = 0; j < 96; ++j) acc += g[j] * w[j * 288];
        Wf[idx] = acc;
    }
}

// ---------------- phase A: gather + GRU + attn projections + exps ----------
// Block = 384 threads = 4 rows x 96 h. Grid = 256.
__global__ __launch_bounds__(384) void gru_kernel(
    const float* __restrict__ xA, const int* __restrict__ deg,
    const int* __restrict__ bucket,
    const float* __restrict__ Wf, const float* __restrict__ Wt_hh,
    const float* __restrict__ b_ih, const float* __restrict__ b_hh,
    const float* __restrict__ Wt_a1i, const float* __restrict__ Wt_a1j,
    const float* __restrict__ ba1,
    float* __restrict__ xB, float* __restrict__ Ei, float* __restrict__ EjT)
{
    __shared__ float Pm[4][Hh];
    __shared__ float Xr[4][Hh];
    __shared__ float Xo[4][Hh];
    int tid = threadIdx.x;
    int r = tid / Hh, h = tid - r * Hh;
    int n = blockIdx.x * 4 + r;
    // sparse gather: mean over source rows (duplicates counted, like segment_sum)
    {
        int d = deg[n];
        int dc = d < SLOTS ? d : SLOTS;
        const int* bk = bucket + n * SLOTS;
        float acc = 0.0f;
        for (int s = 0; s < dc; ++s)
            acc += xA[bk[s] * XS + h];
        Pm[r][h] = acc * __builtin_amdgcn_rcpf(fmaxf((float)d, 1.0f));
        Xr[r][h] = xA[n * XS + h];
    }
    __syncthreads();
    // GRU cell
    {
        const float* Pr = Pm[r];
        const float* xr = Xr[r];
        const float* pf = Wf + h;
        const float* ph = Wt_hh + h;
        float gir = b_ih[h], giz = b_ih[Hh + h], gin = b_ih[2 * Hh + h];
        float ghr = b_hh[h], ghz = b_hh[Hh + h], ghn = b_hh[2 * Hh + h];
        for (int k = 0; k < Hh; ++k) {
            float a = Pr[k];
            float xv = xr[k];
            int o = k * 288;
            gir += a * pf[o];
            giz += a * pf[o + 96];
            gin += a * pf[o + 192];
            ghr += xv * ph[o];
            ghz += xv * ph[o + 96];
            ghn += xv * ph[o + 192];
        }
        float rr = sigf(gir + ghr);
        float z = sigf(giz + ghz);
        float nn2 = tanhfast(gin + rr * ghn);
        float xo = (1.0f - z) * nn2 + z * xr[h];
        xB[n * XS + h] = xo;
        Xo[r][h] = xo;
    }
    __syncthreads();
    // attention projections + exp
    {
        const float* row = Xo[r];
        const float* wi = Wt_a1i + h;
        const float* wj = Wt_a1j + h;
        float a = 0.0f, bb = 0.0f;
        for (int k = 0; k < Hh; ++k) {
            float xv = row[k];
            a += xv * wi[k * 96];
            bb += xv * wj[k * 96];
        }
        Ei[n * Hh + h] = __expf(-(a + ba1[h]));
        EjT[h * Nn + n] = __expf(-bb);
    }
}

// ---------------- phase B: coeffs (4 rows in LDS) + row-GEMM -> xA ---------
// Block = 512 threads, 4 rows/block, grid = 256.
// sm layout (floats): wa2[96] @0, eis[4*96] @96, C[4*1024] @480, red[4*4*96] @4576
#define SM_WA2 0
#define SM_EIS 96
#define SM_C   480
#define SM_RED 4576
__global__ __launch_bounds__(512) void attn_kernel(
    const float* __restrict__ Ei, const float* __restrict__ EjT,
    const float* __restrict__ Wa2, const float* __restrict__ ba2,
    const int* __restrict__ adj, const float* __restrict__ xB,
    float* __restrict__ xA)
{
    __shared__ float sm[4576 + 1536];
    int tid = threadIdx.x;
    int i0 = blockIdx.x * 4;
    if (tid < Hh) sm[SM_WA2 + tid] = Wa2[tid];
    if (tid < 4 * Hh) {
        int r = tid / Hh, h = tid - r * Hh;
        sm[SM_EIS + tid] = Ei[(i0 + r) * Hh + h];
    }
    __syncthreads();
    // coeffs: each thread owns 2 consecutive j for all 4 rows
    {
        int j2 = tid * 2;
        float a0 = 0.f, a1 = 0.f, a2 = 0.f, a3 = 0.f;
        float b0 = 0.f, b1 = 0.f, b2_ = 0.f, b3 = 0.f;
        const float* eis = sm + SM_EIS;
#pragma unroll 2
        for (int k = 0; k < Hh; ++k) {
            float2 e = *(const float2*)(EjT + k * Nn + j2);
            float wk = sm[SM_WA2 + k];
            float e0 = eis[k];
            float e1 = eis[96 + k];
            float e2 = eis[192 + k];
            float e3 = eis[288 + k];
            a0 += __builtin_amdgcn_rcpf(fmaf(e0, e.x, 1.0f)) * wk;
            b0 += __builtin_amdgcn_rcpf(fmaf(e0, e.y, 1.0f)) * wk;
            a1 += __builtin_amdgcn_rcpf(fmaf(e1, e.x, 1.0f)) * wk;
            b1 += __builtin_amdgcn_rcpf(fmaf(e1, e.y, 1.0f)) * wk;
            a2 += __builtin_amdgcn_rcpf(fmaf(e2, e.x, 1.0f)) * wk;
            b2_ += __builtin_amdgcn_rcpf(fmaf(e2, e.y, 1.0f)) * wk;
            a3 += __builtin_amdgcn_rcpf(fmaf(e3, e.x, 1.0f)) * wk;
            b3 += __builtin_amdgcn_rcpf(fmaf(e3, e.y, 1.0f)) * wk;
        }
        float bb = ba2[0];
        int2 m0 = *(const int2*)(adj + (i0 + 0) * Nn + j2);
        int2 m1 = *(const int2*)(adj + (i0 + 1) * Nn + j2);
        int2 m2 = *(const int2*)(adj + (i0 + 2) * Nn + j2);
        int2 m3 = *(const int2*)(adj + (i0 + 3) * Nn + j2);
        sm[SM_C + 0 * Nn + j2]     = (m0.x == 1) ? sigf(a0 + bb) : 0.0f;
        sm[SM_C + 0 * Nn + j2 + 1] = (m0.y == 1) ? sigf(b0 + bb) : 0.0f;
        sm[SM_C + 1 * Nn + j2]     = (m1.x == 1) ? sigf(a1 + bb) : 0.0f;
        sm[SM_C + 1 * Nn + j2 + 1] = (m1.y == 1) ? sigf(b1 + bb) : 0.0f;
        sm[SM_C + 2 * Nn + j2]     = (m2.x == 1) ? sigf(a2 + bb) : 0.0f;
        sm[SM_C + 2 * Nn + j2 + 1] = (m2.y == 1) ? sigf(b2_ + bb) : 0.0f;
        sm[SM_C + 3 * Nn + j2]     = (m3.x == 1) ? sigf(a3 + bb) : 0.0f;
        sm[SM_C + 3 * Nn + j2 + 1] = (m3.y == 1) ? sigf(b3 + bb) : 0.0f;
    }
    __syncthreads();
    // row-GEMM: xA[i0+r, h] = sum_j C[r][j] * xB[j, h]
    // thread = (q = tid>>7 in 0..3 j-quarter, h = tid&127; active h<96)
    {
        int q = tid >> 7;
        int h = tid & 127;
        float acc0 = 0.f, acc1 = 0.f, acc2 = 0.f, acc3 = 0.f;
        if (h < Hh) {
            const float* xc = xB + h;
            int jb = q * 256;
            const float* c0 = sm + SM_C + 0 * Nn + jb;
            const float* c1 = sm + SM_C + 1 * Nn + jb;
            const float* c2 = sm + SM_C + 2 * Nn + jb;
            const float* c3 = sm + SM_C + 3 * Nn + jb;
#pragma unroll 4
            for (int j = 0; j < 256; ++j) {
                float xv = xc[(jb + j) * XS];
                acc0 += c0[j] * xv;
                acc1 += c1[j] * xv;
                acc2 += c2[j] * xv;
                acc3 += c3[j] * xv;
            }
            sm[SM_RED + (q * 4 + 0) * Hh + h] = acc0;
            sm[SM_RED + (q * 4 + 1) * Hh + h] = acc1;
            sm[SM_RED + (q * 4 + 2) * Hh + h] = acc2;
            sm[SM_RED + (q * 4 + 3) * Hh + h] = acc3;
        }
        __syncthreads();
        if (q == 0 && h < Hh) {
#pragma unroll
            for (int r = 0; r < 4; ++r) {
                float v = sm[SM_RED + r * Hh + h]
                        + sm[SM_RED + (4 + r) * Hh + h]
                        + sm[SM_RED + (8 + r) * Hh + h]
                        + sm[SM_RED + (12 + r) * Hh + h];
                xA[(i0 + r) * XS + h] = v;
            }
        }
    }
}

// ---------------- head: lin1 + lin2 + two sigmoid dots, row-local ----------
__global__ __launch_bounds__(384) void head_kernel(
    const float* __restrict__ xA,
    const float* __restrict__ Wt_o1, const float* __restrict__ bo1,
    const float* __restrict__ Wt_o2, const float* __restrict__ bo2,
    const float* __restrict__ Wp1, const float* __restrict__ bp1,
    const float* __restrict__ Wp2, const float* __restrict__ bp2,
    float* __restrict__ out)
{
    __shared__ float xr[4][Hh];
    __shared__ float t1[4][Hh];
    __shared__ float t2[4][Hh];
    int tid = threadIdx.x;
    int r = tid / Hh, h = tid - r * Hh;
    int n = blockIdx.x * 4 + r;
    xr[r][h] = xA[n * XS + h];
    __syncthreads();
    {
        const float* w = Wt_o1 + h;
        float acc = bo1[h];
        for (int k = 0; k < Hh; ++k) acc += xr[r][k] * w[k * 96];
        t1[r][h] = leakyf(acc);
    }
    __syncthreads();
    {
        const float* w = Wt_o2 + h;
        float acc = bo2[h];
        for (int k = 0; k < Hh; ++k) acc += t1[r][k] * w[k * 96];
        t2[r][h] = leakyf(acc);
    }
    __syncthreads();
    if (h == 0) {
        float s1 = 0.f;
        for (int k = 0; k < Hh; ++k) s1 += t2[r][k] * Wp1[k];
        out[n] = sigf(s1 + bp1[0]);
    } else if (h == 1) {
        float s2 = 0.f;
        for (int k = 0; k < Hh; ++k) s2 += t2[r][k] * Wp2[k];
        out[Nn + n] = sigf(s2 + bp2[0]);
    }
}

extern "C" void kernel_launch(void* const* d_in, const int* in_sizes, int n_in,
                              void* d_out, int out_size, void* d_ws, size_t ws_size,
                              hipStream_t stream)
{
    const float* x_in   = (const float*)d_in[0];
    const int*   ei     = (const int*)d_in[1];
    const int*   adj    = (const int*)d_in[2];
    const float* W_init = (const float*)d_in[3];
    const float* b_init = (const float*)d_in[4];
    const float* W_ggc  = (const float*)d_in[5];
    const float* W_ih   = (const float*)d_in[6];
    const float* W_hh   = (const float*)d_in[7];
    const float* b_ih   = (const float*)d_in[8];
    const float* b_hh   = (const float*)d_in[9];
    const float* Wa1    = (const float*)d_in[10];
    const float* ba1    = (const float*)d_in[11];
    const float* Wa2    = (const float*)d_in[12];
    const float* ba2    = (const float*)d_in[13];
    const float* Wo1    = (const float*)d_in[14];
    const float* bo1    = (const float*)d_in[15];
    const float* Wo2    = (const float*)d_in[16];
    const float* bo2    = (const float*)d_in[17];
    const float* Wp1    = (const float*)d_in[18];
    const float* bp1    = (const float*)d_in[19];
    const float* Wp2    = (const float*)d_in[20];
    const float* bp2    = (const float*)d_in[21];
    float* out = (float*)d_out;

    // workspace layout (floats/ints), ~2.3 MB total
    float* ws     = (float*)d_ws;
    float* xA     = ws;                     // (N, XS)
    float* xB     = xA + Nn * XS;           // (N, XS)
    float* Ei     = xB + Nn * XS;           // (N, 96)
    float* EjT    = Ei + NH;                // (96, N)
    float* Wt_ih  = EjT + NH;               // 96*288 (temp for Wf fold)
    float* Wt_hh  = Wt_ih + 27648;
    float* Wf     = Wt_hh + 27648;
    float* Wt_a1i = Wf + 27648;
    float* Wt_a1j = Wt_a1i + 9216;
    float* Wt_o1  = Wt_a1j + 9216;
    float* Wt_o2  = Wt_o1 + 9216;
    int*   deg    = (int*)(Wt_o2 + 9216);   // (N)
    int*   bucket = deg + Nn;               // (N, SLOTS)

    setup1_kernel<<<(NH + 255) / 256, 256, 0, stream>>>(
        W_ih, W_hh, Wa1, Wo1, Wo2, x_in, W_init, b_init,
        Wt_ih, Wt_hh, Wt_a1i, Wt_a1j, Wt_o1, Wt_o2, deg, xA);
    setup2_kernel<<<(Ee + 27648 + 255) / 256, 256, 0, stream>>>(
        ei, W_ggc, Wt_ih, deg, bucket, Wf);

    for (int u = 0; u < 2; ++u) {
        gru_kernel<<<Nn / 4, 384, 0, stream>>>(
            xA, deg, bucket, Wf, Wt_hh, b_ih, b_hh,
            Wt_a1i, Wt_a1j, ba1, xB, Ei, EjT);
        attn_kernel<<<Nn / 4, 512, 0, stream>>>(
            Ei, EjT, Wa2, ba2, adj, xB, xA);
    }

    head_kernel<<<Nn / 4, 384, 0, stream>>>(
        xA, Wt_o1, bo1, Wt_o2, bo2, Wp1, bp1, Wp2, bp2, out);
}

// Round 7
// 211.319 us; speedup vs baseline: 4.2870x; 1.0781x over previous
//
#include <hip/hip_runtime.h>

// Problem constants (from reference)
#define Nn 1024
#define Hh 96
#define Ee 16384
#define IN_K 9       // IN_RAW-1
#define IN_STRIDE 10 // x is (N, 10), we use first 9 cols
#define NH (Nn * Hh)
#define XS 128       // padded row stride for x-like (N,96) buffers
#define SLOTS 64     // CSR bucket capacity (Poisson(16) degree; P(>64) ~ 0)

__device__ __forceinline__ float sigf(float v) {
    return __builtin_amdgcn_rcpf(1.0f + __expf(-v));
}
__device__ __forceinline__ float tanhfast(float v) {
    float e = __expf(2.0f * v);
    return (e - 1.0f) * __builtin_amdgcn_rcpf(e + 1.0f);
}
__device__ __forceinline__ float leakyf(float v) {
    return v >= 0.0f ? v : 0.01f * v;
}

// ---------------- setup: transposes + Wf fold + init linear + zero deg -----
// Wf computed straight from W_ggc/W_ih (no Wt_ih intermediate).
__global__ __launch_bounds__(256) void setup_kernel(
    const float* __restrict__ W_hh, const float* __restrict__ Wa1,
    const float* __restrict__ Wo1, const float* __restrict__ Wo2,
    const float* __restrict__ W_ggc, const float* __restrict__ W_ih,
    const float* __restrict__ x_in, const float* __restrict__ W_init,
    const float* __restrict__ b_init,
    float* __restrict__ Wt_hh, float* __restrict__ Wt_a1i,
    float* __restrict__ Wt_a1j, float* __restrict__ Wt_o1,
    float* __restrict__ Wt_o2, float* __restrict__ Wf,
    int* __restrict__ deg, float* __restrict__ xA)
{
    int gt = blockIdx.x * 256 + threadIdx.x;
    if (gt < Nn) deg[gt] = 0;
    if (gt < 64512) {   // transposes: Wt_hh 27648 + 4x9216
        int idx = gt;
        if (idx < 27648) {
            int k = idx / 288, c = idx % 288;
            Wt_hh[idx] = W_hh[c * 96 + k];
        } else if ((idx -= 27648) < 9216) {
            int k = idx / 96, h = idx % 96;
            Wt_a1i[idx] = Wa1[h * 192 + k];
        } else if ((idx -= 9216) < 9216) {
            int k = idx / 96, h = idx % 96;
            Wt_a1j[idx] = Wa1[h * 192 + 96 + k];
        } else if ((idx -= 9216) < 9216) {
            int k = idx / 96, j = idx % 96;
            Wt_o1[idx] = Wo1[j * 96 + k];
        } else {
            idx -= 9216;
            int k = idx / 96, j = idx % 96;
            Wt_o2[idx] = Wo2[j * 96 + k];
        }
    }
    if (gt < 27648) {   // Wf[k][c] = sum_j W_ggc[k][j] * W_ih[c][j]
        int k = gt / 288, c = gt % 288;
        const float* g = W_ggc + k * 96;
        const float* w = W_ih + c * 96;
        float acc = 0.0f;
        for (int j = 0; j < 96; ++j) acc += g[j] * w[j];
        Wf[gt] = acc;
    }
    if (gt < NH) {      // init linear
        int n = gt / Hh, j = gt - n * Hh;
        const float* xr = x_in + n * IN_STRIDE;
        const float* wr = W_init + j * IN_K;
        float acc = b_init[j];
#pragma unroll
        for (int k = 0; k < IN_K; ++k) acc += xr[k] * wr[k];
        xA[n * XS + j] = leakyf(acc);
    }
}

// ---------------- edges: CSR bucket scatter (needs zeroed deg) -------------
__global__ __launch_bounds__(256) void edges_kernel(
    const int* __restrict__ ei, int* __restrict__ deg, int* __restrict__ bucket)
{
    int e = blockIdx.x * 256 + threadIdx.x;
    if (e >= Ee) return;
    int src = ei[e];
    int tgt = ei[Ee + e];
    int slot = atomicAdd(&deg[tgt], 1);
    if (slot < SLOTS) bucket[tgt * SLOTS + slot] = src;
}

// ---------------- phase A: gather + GRU + attn projections (split-k) -------
// Block = 384 threads: half = tid/192, r = (tid/96)%2, h = tid%96.
// 2 rows/block, grid = 512. Each thread does the k-half [half*48, half*48+48).
__global__ __launch_bounds__(384) void gru_kernel(
    const float* __restrict__ xA, const int* __restrict__ deg,
    const int* __restrict__ bucket,
    const float* __restrict__ Wf, const float* __restrict__ Wt_hh,
    const float* __restrict__ b_ih, const float* __restrict__ b_hh,
    const float* __restrict__ Wt_a1i, const float* __restrict__ Wt_a1j,
    const float* __restrict__ ba1,
    float* __restrict__ xB, float* __restrict__ Ei, float* __restrict__ EjT)
{
    __shared__ float Pp[2][2][Hh];     // gather partials [half][r][h]
    __shared__ float Pm[2][Hh];        // combined mean [r][k]
    __shared__ float Xr[2][Hh];        // x row [r][k]
    __shared__ float Xo[2][Hh];        // GRU output row
    __shared__ float red6[2][2][Hh][6];// dot partials [half][r][h][gate]
    __shared__ float redp[2][2][Hh][2];// projection partials
    int tid = threadIdx.x;
    int half = tid / 192;
    int loc = tid - half * 192;
    int r = loc / Hh, h = loc - r * Hh;
    int n = blockIdx.x * 2 + r;
    // gather partial (slots strided by half) + x row load (half 0)
    {
        int d = deg[n];
        int dc = d < SLOTS ? d : SLOTS;
        const int* bk = bucket + n * SLOTS;
        float acc = 0.0f;
        for (int s = half; s < dc; s += 2)
            acc += xA[bk[s] * XS + h];
        Pp[half][r][h] = acc;
        if (half == 0) Xr[r][h] = xA[n * XS + h];
    }
    __syncthreads();
    if (half == 0) {
        float inv = __builtin_amdgcn_rcpf(fmaxf((float)deg[n], 1.0f));
        Pm[r][h] = (Pp[0][r][h] + Pp[1][r][h]) * inv;
    }
    __syncthreads();
    // GRU partial dots over this thread's k-half
    {
        const float* Pr = Pm[r];
        const float* xr = Xr[r];
        const float* pf = Wf + h;
        const float* ph = Wt_hh + h;
        float gir = 0.f, giz = 0.f, gin = 0.f;
        float ghr = 0.f, ghz = 0.f, ghn = 0.f;
        int k0 = half * 48;
#pragma unroll 4
        for (int k = k0; k < k0 + 48; ++k) {
            float a = Pr[k];
            float xv = xr[k];
            int o = k * 288;
            gir += a * pf[o];
            giz += a * pf[o + 96];
            gin += a * pf[o + 192];
            ghr += xv * ph[o];
            ghz += xv * ph[o + 96];
            ghn += xv * ph[o + 192];
        }
        red6[half][r][h][0] = gir;
        red6[half][r][h][1] = giz;
        red6[half][r][h][2] = gin;
        red6[half][r][h][3] = ghr;
        red6[half][r][h][4] = ghz;
        red6[half][r][h][5] = ghn;
    }
    __syncthreads();
    if (half == 0) {
        float gir = b_ih[h] + red6[0][r][h][0] + red6[1][r][h][0];
        float giz = b_ih[Hh + h] + red6[0][r][h][1] + red6[1][r][h][1];
        float gin = b_ih[2 * Hh + h] + red6[0][r][h][2] + red6[1][r][h][2];
        float ghr = b_hh[h] + red6[0][r][h][3] + red6[1][r][h][3];
        float ghz = b_hh[Hh + h] + red6[0][r][h][4] + red6[1][r][h][4];
        float ghn = b_hh[2 * Hh + h] + red6[0][r][h][5] + red6[1][r][h][5];
        float rr = sigf(gir + ghr);
        float z = sigf(giz + ghz);
        float nn2 = tanhfast(gin + rr * ghn);
        float xo = (1.0f - z) * nn2 + z * Xr[r][h];
        xB[n * XS + h] = xo;
        Xo[r][h] = xo;
    }
    __syncthreads();
    // attention projection partials
    {
        const float* row = Xo[r];
        const float* wi = Wt_a1i + h;
        const float* wj = Wt_a1j + h;
        float a = 0.0f, bb = 0.0f;
        int k0 = half * 48;
#pragma unroll 4
        for (int k = k0; k < k0 + 48; ++k) {
            float xv = row[k];
            a += xv * wi[k * 96];
            bb += xv * wj[k * 96];
        }
        redp[half][r][h][0] = a;
        redp[half][r][h][1] = bb;
    }
    __syncthreads();
    if (half == 0) {
        float a = redp[0][r][h][0] + redp[1][r][h][0];
        float bb = redp[0][r][h][1] + redp[1][r][h][1];
        Ei[n * Hh + h] = __expf(-(a + ba1[h]));
        EjT[h * Nn + n] = __expf(-bb);
    }
}

// ---------------- phase B: coeffs + row-GEMM (+ optional fused head) -------
// Block = 512 threads, 2 rows/block, grid = 512 (2 blocks/CU).
template <bool HEAD>
__global__ __launch_bounds__(512) void attn_kernel(
    const float* __restrict__ Ei, const float* __restrict__ EjT,
    const float* __restrict__ Wa2, const float* __restrict__ ba2,
    const int* __restrict__ adj, const float* __restrict__ xB,
    float* __restrict__ xA,
    const float* __restrict__ Wt_o1, const float* __restrict__ bo1,
    const float* __restrict__ Wt_o2, const float* __restrict__ bo2,
    const float* __restrict__ Wp1, const float* __restrict__ bp1,
    const float* __restrict__ Wp2, const float* __restrict__ bp2,
    float* __restrict__ out)
{
    __shared__ __align__(16) float wa2[Hh];
    __shared__ __align__(16) float eis[2][Hh];
    __shared__ __align__(16) float C[2][Nn];
    __shared__ float red[4][2][Hh];
    __shared__ float xout[2][Hh];
    __shared__ float t1[2][Hh];
    __shared__ float t2[2][Hh];
    int tid = threadIdx.x;
    int i0 = blockIdx.x * 2;
    if (tid < Hh) wa2[tid] = Wa2[tid];
    if (tid < 2 * Hh) {
        int r = tid / Hh, h = tid - r * Hh;
        eis[r][h] = Ei[(i0 + r) * Hh + h];
    }
    __syncthreads();
    // coeffs: thread = (row = tid>>8, 4 consecutive j)
    {
        int row = tid >> 8;
        int jj = (tid & 255) * 4;
        int4 mk = *(const int4*)(adj + (i0 + row) * Nn + jj);  // prefetch mask
        float s0 = 0.f, s1 = 0.f, s2 = 0.f, s3 = 0.f;
        const float* er = eis[row];
#pragma unroll 4
        for (int k = 0; k < Hh; ++k) {
            float4 e4 = *(const float4*)(EjT + k * Nn + jj);
            float eik = er[k];
            float wk = wa2[k];
            s0 += __builtin_amdgcn_rcpf(fmaf(eik, e4.x, 1.0f)) * wk;
            s1 += __builtin_amdgcn_rcpf(fmaf(eik, e4.y, 1.0f)) * wk;
            s2 += __builtin_amdgcn_rcpf(fmaf(eik, e4.z, 1.0f)) * wk;
            s3 += __builtin_amdgcn_rcpf(fmaf(eik, e4.w, 1.0f)) * wk;
        }
        float b2 = ba2[0];
        float4 c;
        c.x = (mk.x == 1) ? sigf(s0 + b2) : 0.0f;
        c.y = (mk.y == 1) ? sigf(s1 + b2) : 0.0f;
        c.z = (mk.z == 1) ? sigf(s2 + b2) : 0.0f;
        c.w = (mk.w == 1) ? sigf(s3 + b2) : 0.0f;
        *(float4*)(&C[row][jj]) = c;
    }
    __syncthreads();
    // row-GEMM: thread = (q = tid>>7 j-quarter, h = tid&127)
    {
        int q = tid >> 7;
        int h = tid & 127;
        if (h < Hh) {
            const float* xc = xB + h;
            int jb = q * 256;
            const float* c0 = &C[0][jb];
            const float* c1 = &C[1][jb];
            float acc0 = 0.f, acc1 = 0.f;
#pragma unroll 4
            for (int j = 0; j < 256; ++j) {
                float xv = xc[(jb + j) * XS];
                acc0 += c0[j] * xv;
                acc1 += c1[j] * xv;
            }
            red[q][0][h] = acc0;
            red[q][1][h] = acc1;
        }
        __syncthreads();
        if (q == 0 && h < Hh) {
#pragma unroll
            for (int r = 0; r < 2; ++r) {
                float v = red[0][r][h] + red[1][r][h] + red[2][r][h] + red[3][r][h];
                if (HEAD) xout[r][h] = v;
                else      xA[(i0 + r) * XS + h] = v;
            }
        }
    }
    if (HEAD) {
        __syncthreads();
        if (tid < 2 * Hh) {
            int r = tid / Hh, h = tid - r * Hh;
            const float* w = Wt_o1 + h;
            float acc = bo1[h];
            for (int k = 0; k < Hh; ++k) acc += xout[r][k] * w[k * 96];
            t1[r][h] = leakyf(acc);
        }
        __syncthreads();
        if (tid < 2 * Hh) {
            int r = tid / Hh, h = tid - r * Hh;
            const float* w = Wt_o2 + h;
            float acc = bo2[h];
            for (int k = 0; k < Hh; ++k) acc += t1[r][k] * w[k * 96];
            t2[r][h] = leakyf(acc);
        }
        __syncthreads();
        if (tid < 4) {
            int r = tid >> 1, which = tid & 1;
            const float* wp = which ? Wp2 : Wp1;
            float acc = 0.f;
            for (int k = 0; k < Hh; ++k) acc += t2[r][k] * wp[k];
            float b = which ? bp2[0] : bp1[0];
            out[which * Nn + i0 + r] = sigf(acc + b);
        }
    }
}

extern "C" void kernel_launch(void* const* d_in, const int* in_sizes, int n_in,
                              void* d_out, int out_size, void* d_ws, size_t ws_size,
                              hipStream_t stream)
{
    const float* x_in   = (const float*)d_in[0];
    const int*   ei     = (const int*)d_in[1];
    const int*   adj    = (const int*)d_in[2];
    const float* W_init = (const float*)d_in[3];
    const float* b_init = (const float*)d_in[4];
    const float* W_ggc  = (const float*)d_in[5];
    const float* W_ih   = (const float*)d_in[6];
    const float* W_hh   = (const float*)d_in[7];
    const float* b_ih   = (const float*)d_in[8];
    const float* b_hh   = (const float*)d_in[9];
    const float* Wa1    = (const float*)d_in[10];
    const float* ba1    = (const float*)d_in[11];
    const float* Wa2    = (const float*)d_in[12];
    const float* ba2    = (const float*)d_in[13];
    const float* Wo1    = (const float*)d_in[14];
    const float* bo1    = (const float*)d_in[15];
    const float* Wo2    = (const float*)d_in[16];
    const float* bo2    = (const float*)d_in[17];
    const float* Wp1    = (const float*)d_in[18];
    const float* bp1    = (const float*)d_in[19];
    const float* Wp2    = (const float*)d_in[20];
    const float* bp2    = (const float*)d_in[21];
    float* out = (float*)d_out;

    // workspace layout, ~2 MB
    float* ws     = (float*)d_ws;
    float* xA     = ws;                     // (N, XS)
    float* xB     = xA + Nn * XS;           // (N, XS)
    float* Ei     = xB + Nn * XS;           // (N, 96)
    float* EjT    = Ei + NH;                // (96, N)
    float* Wt_hh  = EjT + NH;               // 96*288
    float* Wf     = Wt_hh + 27648;          // 96*288
    float* Wt_a1i = Wf + 27648;             // 96*96
    float* Wt_a1j = Wt_a1i + 9216;
    float* Wt_o1  = Wt_a1j + 9216;
    float* Wt_o2  = Wt_o1 + 9216;
    int*   deg    = (int*)(Wt_o2 + 9216);   // (N)
    int*   bucket = deg + Nn;               // (N, SLOTS)

    setup_kernel<<<(NH + 255) / 256, 256, 0, stream>>>(
        W_hh, Wa1, Wo1, Wo2, W_ggc, W_ih, x_in, W_init, b_init,
        Wt_hh, Wt_a1i, Wt_a1j, Wt_o1, Wt_o2, Wf, deg, xA);
    edges_kernel<<<(Ee + 255) / 256, 256, 0, stream>>>(ei, deg, bucket);

    gru_kernel<<<Nn / 2, 384, 0, stream>>>(
        xA, deg, bucket, Wf, Wt_hh, b_ih, b_hh, Wt_a1i, Wt_a1j, ba1,
        xB, Ei, EjT);
    attn_kernel<false><<<Nn / 2, 512, 0, stream>>>(
        Ei, EjT, Wa2, ba2, adj, xB, xA,
        nullptr, nullptr, nullptr, nullptr, nullptr, nullptr, nullptr, nullptr,
        nullptr);
    gru_kernel<<<Nn / 2, 384, 0, stream>>>(
        xA, deg, bucket, Wf, Wt_hh, b_ih, b_hh, Wt_a1i, Wt_a1j, ba1,
        xB, Ei, EjT);
    attn_kernel<true><<<Nn / 2, 512, 0, stream>>>(
        Ei, EjT, Wa2, ba2, adj, xB, xA,
        Wt_o1, bo1, Wt_o2, bo2, Wp1, bp1, Wp2, bp2, out);
}

// Round 8
// 197.343 us; speedup vs baseline: 4.5906x; 1.0708x over previous
//
#include <hip/hip_runtime.h>

// Problem constants (from reference)
#define Nn 1024
#define Hh 96
#define Ee 16384
#define IN_K 9       // IN_RAW-1
#define IN_STRIDE 10 // x is (N, 10), we use first 9 cols
#define NH (Nn * Hh)
#define XS 128       // padded row stride for x-like (N,96) buffers
#define SLOTS 64     // CSR bucket capacity (Poisson(16) degree; P(>64) ~ 0)

__device__ __forceinline__ float sigf(float v) {
    return __builtin_amdgcn_rcpf(1.0f + __expf(-v));
}
__device__ __forceinline__ float tanhfast(float v) {
    float e = __expf(2.0f * v);
    return (e - 1.0f) * __builtin_amdgcn_rcpf(e + 1.0f);
}
__device__ __forceinline__ float leakyf(float v) {
    return v >= 0.0f ? v : 0.01f * v;
}

// ---------------- setup: transposes + Wf fold + init linear + zero deg -----
__global__ __launch_bounds__(256) void setup_kernel(
    const float* __restrict__ W_hh, const float* __restrict__ Wa1,
    const float* __restrict__ Wo1, const float* __restrict__ Wo2,
    const float* __restrict__ W_ggc, const float* __restrict__ W_ih,
    const float* __restrict__ x_in, const float* __restrict__ W_init,
    const float* __restrict__ b_init,
    float* __restrict__ Wt_hh, float* __restrict__ Wt_a1i,
    float* __restrict__ Wt_a1j, float* __restrict__ Wt_o1,
    float* __restrict__ Wt_o2, float* __restrict__ Wf,
    int* __restrict__ deg, float* __restrict__ xA)
{
    int gt = blockIdx.x * 256 + threadIdx.x;
    if (gt < Nn) deg[gt] = 0;
    if (gt < 64512) {   // transposes: Wt_hh 27648 + 4x9216
        int idx = gt;
        if (idx < 27648) {
            int k = idx / 288, c = idx % 288;
            Wt_hh[idx] = W_hh[c * 96 + k];
        } else if ((idx -= 27648) < 9216) {
            int k = idx / 96, h = idx % 96;
            Wt_a1i[idx] = Wa1[h * 192 + k];
        } else if ((idx -= 9216) < 9216) {
            int k = idx / 96, h = idx % 96;
            Wt_a1j[idx] = Wa1[h * 192 + 96 + k];
        } else if ((idx -= 9216) < 9216) {
            int k = idx / 96, j = idx % 96;
            Wt_o1[idx] = Wo1[j * 96 + k];
        } else {
            idx -= 9216;
            int k = idx / 96, j = idx % 96;
            Wt_o2[idx] = Wo2[j * 96 + k];
        }
    }
    if (gt < 27648) {   // Wf[k][c] = sum_j W_ggc[k][j] * W_ih[c][j]
        int k = gt / 288, c = gt % 288;
        const float* g = W_ggc + k * 96;
        const float* w = W_ih + c * 96;
        float acc = 0.0f;
        for (int j = 0; j < 96; ++j) acc += g[j] * w[j];
        Wf[gt] = acc;
    }
    if (gt < NH) {      // init linear
        int n = gt / Hh, j = gt - n * Hh;
        const float* xr = x_in + n * IN_STRIDE;
        const float* wr = W_init + j * IN_K;
        float acc = b_init[j];
#pragma unroll
        for (int k = 0; k < IN_K; ++k) acc += xr[k] * wr[k];
        xA[n * XS + j] = leakyf(acc);
    }
}

// ---------------- edges: CSR bucket scatter (needs zeroed deg) -------------
__global__ __launch_bounds__(256) void edges_kernel(
    const int* __restrict__ ei, int* __restrict__ deg, int* __restrict__ bucket)
{
    int e = blockIdx.x * 256 + threadIdx.x;
    if (e >= Ee) return;
    int src = ei[e];
    int tgt = ei[Ee + e];
    int slot = atomicAdd(&deg[tgt], 1);
    if (slot < SLOTS) bucket[tgt * SLOTS + slot] = src;
}

// ---------------- phase A: gather + GRU + attn projections (split-k) -------
// Block = 384 threads: half = tid/192, r = (tid/96)%2, h = tid%96.
// 2 rows/block, grid = 512. Also zeroes xZero (the attn accumulation target).
__global__ __launch_bounds__(384) void gru_kernel(
    const float* __restrict__ xA, const int* __restrict__ deg,
    const int* __restrict__ bucket,
    const float* __restrict__ Wf, const float* __restrict__ Wt_hh,
    const float* __restrict__ b_ih, const float* __restrict__ b_hh,
    const float* __restrict__ Wt_a1i, const float* __restrict__ Wt_a1j,
    const float* __restrict__ ba1,
    float* __restrict__ xB, float* __restrict__ Ei, float* __restrict__ EjT,
    float* __restrict__ xZero)
{
    __shared__ float Pp[2][2][Hh];     // gather partials [half][r][h]
    __shared__ float Pm[2][Hh];        // combined mean [r][k]
    __shared__ float Xr[2][Hh];        // x row [r][k]
    __shared__ float Xo[2][Hh];        // GRU output row
    __shared__ float red6[2][2][Hh][6];// dot partials [half][r][h][gate]
    __shared__ float redp[2][2][Hh][2];// projection partials
    int tid = threadIdx.x;
    int half = tid / 192;
    int loc = tid - half * 192;
    int r = loc / Hh, h = loc - r * Hh;
    int n = blockIdx.x * 2 + r;
    // gather partial (slots strided by half) + x row load (half 0)
    {
        int d = deg[n];
        int dc = d < SLOTS ? d : SLOTS;
        const int* bk = bucket + n * SLOTS;
        float acc = 0.0f;
        for (int s = half; s < dc; s += 2)
            acc += xA[bk[s] * XS + h];
        Pp[half][r][h] = acc;
        if (half == 0) Xr[r][h] = xA[n * XS + h];
        else           xZero[n * XS + h] = 0.0f;   // pre-zero attn target
    }
    __syncthreads();
    if (half == 0) {
        float inv = __builtin_amdgcn_rcpf(fmaxf((float)deg[n], 1.0f));
        Pm[r][h] = (Pp[0][r][h] + Pp[1][r][h]) * inv;
    }
    __syncthreads();
    // GRU partial dots over this thread's k-half
    {
        const float* Pr = Pm[r];
        const float* xr = Xr[r];
        const float* pf = Wf + h;
        const float* ph = Wt_hh + h;
        float gir = 0.f, giz = 0.f, gin = 0.f;
        float ghr = 0.f, ghz = 0.f, ghn = 0.f;
        int k0 = half * 48;
#pragma unroll 4
        for (int k = k0; k < k0 + 48; ++k) {
            float a = Pr[k];
            float xv = xr[k];
            int o = k * 288;
            gir += a * pf[o];
            giz += a * pf[o + 96];
            gin += a * pf[o + 192];
            ghr += xv * ph[o];
            ghz += xv * ph[o + 96];
            ghn += xv * ph[o + 192];
        }
        red6[half][r][h][0] = gir;
        red6[half][r][h][1] = giz;
        red6[half][r][h][2] = gin;
        red6[half][r][h][3] = ghr;
        red6[half][r][h][4] = ghz;
        red6[half][r][h][5] = ghn;
    }
    __syncthreads();
    if (half == 0) {
        float gir = b_ih[h] + red6[0][r][h][0] + red6[1][r][h][0];
        float giz = b_ih[Hh + h] + red6[0][r][h][1] + red6[1][r][h][1];
        float gin = b_ih[2 * Hh + h] + red6[0][r][h][2] + red6[1][r][h][2];
        float ghr = b_hh[h] + red6[0][r][h][3] + red6[1][r][h][3];
        float ghz = b_hh[Hh + h] + red6[0][r][h][4] + red6[1][r][h][4];
        float ghn = b_hh[2 * Hh + h] + red6[0][r][h][5] + red6[1][r][h][5];
        float rr = sigf(gir + ghr);
        float z = sigf(giz + ghz);
        float nn2 = tanhfast(gin + rr * ghn);
        float xo = (1.0f - z) * nn2 + z * Xr[r][h];
        xB[n * XS + h] = xo;
        Xo[r][h] = xo;
    }
    __syncthreads();
    // attention projection partials
    {
        const float* row = Xo[r];
        const float* wi = Wt_a1i + h;
        const float* wj = Wt_a1j + h;
        float a = 0.0f, bb = 0.0f;
        int k0 = half * 48;
#pragma unroll 4
        for (int k = k0; k < k0 + 48; ++k) {
            float xv = row[k];
            a += xv * wi[k * 96];
            bb += xv * wj[k * 96];
        }
        redp[half][r][h][0] = a;
        redp[half][r][h][1] = bb;
    }
    __syncthreads();
    if (half == 0) {
        float a = redp[0][r][h][0] + redp[1][r][h][0];
        float bb = redp[0][r][h][1] + redp[1][r][h][1];
        Ei[n * Hh + h] = __expf(-(a + ba1[h]));
        EjT[h * Nn + n] = __expf(-bb);
    }
}

// ---------------- phase B: coeffs + row-GEMM, 4 rows x half-j per block ----
// Grid = 512 (256 i-groups x 2 j-halves), 512 threads, 2 blocks/CU.
// Each thread owns ONE j; one EjT load feeds all 4 rows (4 rcp / load).
// Partial row sums atomically accumulated into pre-zeroed xOut.
__global__ __launch_bounds__(512) void attn_kernel(
    const float* __restrict__ Ei, const float* __restrict__ EjT,
    const float* __restrict__ Wa2, const float* __restrict__ ba2,
    const int* __restrict__ adj, const float* __restrict__ xB,
    float* __restrict__ xOut)
{
    __shared__ __align__(16) float wa2[Hh];
    __shared__ __align__(16) float eis[4][Hh];
    __shared__ __align__(16) float C[4][512];
    __shared__ float red[4][4][Hh];
    int tid = threadIdx.x;
    int ig = blockIdx.x >> 1;
    int jh = blockIdx.x & 1;
    int i0 = ig * 4;
    int jbase = jh * 512;
    if (tid < Hh) wa2[tid] = Wa2[tid];
    if (tid < 4 * Hh) {
        int r = tid / Hh, h = tid - r * Hh;
        eis[r][h] = Ei[(i0 + r) * Hh + h];
    }
    __syncthreads();
    // coeffs: thread owns j = jbase + tid, computes all 4 rows
    {
        int j = jbase + tid;
        int m0 = adj[(i0 + 0) * Nn + j];
        int m1 = adj[(i0 + 1) * Nn + j];
        int m2 = adj[(i0 + 2) * Nn + j];
        int m3 = adj[(i0 + 3) * Nn + j];
        float s0 = 0.f, s1 = 0.f, s2 = 0.f, s3 = 0.f;
#pragma unroll 4
        for (int k = 0; k < Hh; ++k) {
            float e = EjT[k * Nn + j];
            float wk = wa2[k];
            s0 += __builtin_amdgcn_rcpf(fmaf(eis[0][k], e, 1.0f)) * wk;
            s1 += __builtin_amdgcn_rcpf(fmaf(eis[1][k], e, 1.0f)) * wk;
            s2 += __builtin_amdgcn_rcpf(fmaf(eis[2][k], e, 1.0f)) * wk;
            s3 += __builtin_amdgcn_rcpf(fmaf(eis[3][k], e, 1.0f)) * wk;
        }
        float b2 = ba2[0];
        C[0][tid] = (m0 == 1) ? sigf(s0 + b2) : 0.0f;
        C[1][tid] = (m1 == 1) ? sigf(s1 + b2) : 0.0f;
        C[2][tid] = (m2 == 1) ? sigf(s2 + b2) : 0.0f;
        C[3][tid] = (m3 == 1) ? sigf(s3 + b2) : 0.0f;
    }
    __syncthreads();
    // row-GEMM over this j-half: thread = (q = tid>>7 j-quarter of 128, h)
    {
        int q = tid >> 7;
        int h = tid & 127;
        if (h < Hh) {
            int jq = q * 128;
            const float* xc = xB + (jbase + jq) * XS + h;
            const float* c0 = &C[0][jq];
            const float* c1 = &C[1][jq];
            const float* c2 = &C[2][jq];
            const float* c3 = &C[3][jq];
            float a0 = 0.f, a1 = 0.f, a2 = 0.f, a3 = 0.f;
#pragma unroll 4
            for (int j = 0; j < 128; ++j) {
                float xv = xc[j * XS];
                a0 += c0[j] * xv;
                a1 += c1[j] * xv;
                a2 += c2[j] * xv;
                a3 += c3[j] * xv;
            }
            red[q][0][h] = a0;
            red[q][1][h] = a1;
            red[q][2][h] = a2;
            red[q][3][h] = a3;
        }
        __syncthreads();
        // thread (q,h) finalizes row q: sum over quarters, one atomic
        if (h < Hh) {
            float v = red[0][q][h] + red[1][q][h] + red[2][q][h] + red[3][q][h];
            atomicAdd(&xOut[(i0 + q) * XS + h], v);
        }
    }
}

// ---------------- head: lin1 + lin2 + two sigmoid dots, row-local ----------
__global__ __launch_bounds__(384) void head_kernel(
    const float* __restrict__ xA,
    const float* __restrict__ Wt_o1, const float* __restrict__ bo1,
    const float* __restrict__ Wt_o2, const float* __restrict__ bo2,
    const float* __restrict__ Wp1, const float* __restrict__ bp1,
    const float* __restrict__ Wp2, const float* __restrict__ bp2,
    float* __restrict__ out)
{
    __shared__ float xr[4][Hh];
    __shared__ float t1[4][Hh];
    __shared__ float t2[4][Hh];
    int tid = threadIdx.x;
    int r = tid / Hh, h = tid - r * Hh;
    int n = blockIdx.x * 4 + r;
    xr[r][h] = xA[n * XS + h];
    __syncthreads();
    {
        const float* w = Wt_o1 + h;
        float acc = bo1[h];
        for (int k = 0; k < Hh; ++k) acc += xr[r][k] * w[k * 96];
        t1[r][h] = leakyf(acc);
    }
    __syncthreads();
    {
        const float* w = Wt_o2 + h;
        float acc = bo2[h];
        for (int k = 0; k < Hh; ++k) acc += t1[r][k] * w[k * 96];
        t2[r][h] = leakyf(acc);
    }
    __syncthreads();
    if (h == 0) {
        float s1 = 0.f;
        for (int k = 0; k < Hh; ++k) s1 += t2[r][k] * Wp1[k];
        out[n] = sigf(s1 + bp1[0]);
    } else if (h == 1) {
        float s2 = 0.f;
        for (int k = 0; k < Hh; ++k) s2 += t2[r][k] * Wp2[k];
        out[Nn + n] = sigf(s2 + bp2[0]);
    }
}

extern "C" void kernel_launch(void* const* d_in, const int* in_sizes, int n_in,
                              void* d_out, int out_size, void* d_ws, size_t ws_size,
                              hipStream_t stream)
{
    const float* x_in   = (const float*)d_in[0];
    const int*   ei     = (const int*)d_in[1];
    const int*   adj    = (const int*)d_in[2];
    const float* W_init = (const float*)d_in[3];
    const float* b_init = (const float*)d_in[4];
    const float* W_ggc  = (const float*)d_in[5];
    const float* W_ih   = (const float*)d_in[6];
    const float* W_hh   = (const float*)d_in[7];
    const float* b_ih   = (const float*)d_in[8];
    const float* b_hh   = (const float*)d_in[9];
    const float* Wa1    = (const float*)d_in[10];
    const float* ba1    = (const float*)d_in[11];
    const float* Wa2    = (const float*)d_in[12];
    const float* ba2    = (const float*)d_in[13];
    const float* Wo1    = (const float*)d_in[14];
    const float* bo1    = (const float*)d_in[15];
    const float* Wo2    = (const float*)d_in[16];
    const float* bo2    = (const float*)d_in[17];
    const float* Wp1    = (const float*)d_in[18];
    const float* bp1    = (const float*)d_in[19];
    const float* Wp2    = (const float*)d_in[20];
    const float* bp2    = (const float*)d_in[21];
    float* out = (float*)d_out;

    // workspace layout, ~2.5 MB
    float* ws     = (float*)d_ws;
    float* xA     = ws;                     // (N, XS)
    float* xB     = xA + Nn * XS;           // (N, XS)
    float* xC     = xB + Nn * XS;           // (N, XS) attn u0 accumulation
    float* Ei     = xC + Nn * XS;           // (N, 96)
    float* EjT    = Ei + NH;                // (96, N)
    float* Wt_hh  = EjT + NH;               // 96*288
    float* Wf     = Wt_hh + 27648;          // 96*288
    float* Wt_a1i = Wf + 27648;             // 96*96
    float* Wt_a1j = Wt_a1i + 9216;
    float* Wt_o1  = Wt_a1j + 9216;
    float* Wt_o2  = Wt_o1 + 9216;
    int*   deg    = (int*)(Wt_o2 + 9216);   // (N)
    int*   bucket = deg + Nn;               // (N, SLOTS)

    setup_kernel<<<(NH + 255) / 256, 256, 0, stream>>>(
        W_hh, Wa1, Wo1, Wo2, W_ggc, W_ih, x_in, W_init, b_init,
        Wt_hh, Wt_a1i, Wt_a1j, Wt_o1, Wt_o2, Wf, deg, xA);
    edges_kernel<<<(Ee + 255) / 256, 256, 0, stream>>>(ei, deg, bucket);

    // unroll 0: xA -> xB -> xC (gru zeroes xC for attn's atomics)
    gru_kernel<<<Nn / 2, 384, 0, stream>>>(
        xA, deg, bucket, Wf, Wt_hh, b_ih, b_hh, Wt_a1i, Wt_a1j, ba1,
        xB, Ei, EjT, xC);
    attn_kernel<<<Nn / 2, 512, 0, stream>>>(
        Ei, EjT, Wa2, ba2, adj, xB, xC);
    // unroll 1: xC -> xB -> xA (gru zeroes xA for attn's atomics)
    gru_kernel<<<Nn / 2, 384, 0, stream>>>(
        xC, deg, bucket, Wf, Wt_hh, b_ih, b_hh, Wt_a1i, Wt_a1j, ba1,
        xB, Ei, EjT, xA);
    attn_kernel<<<Nn / 2, 512, 0, stream>>>(
        Ei, EjT, Wa2, ba2, adj, xB, xA);

    head_kernel<<<Nn / 4, 384, 0, stream>>>(
        xA, Wt_o1, bo1, Wt_o2, bo2, Wp1, bp1, Wp2, bp2, out);
}

// Round 9
// 197.129 us; speedup vs baseline: 4.5955x; 1.0011x over previous
//
#include <hip/hip_runtime.h>

// Problem constants (from reference)
#define Nn 1024
#define Hh 96
#define Ee 16384
#define IN_K 9       // IN_RAW-1
#define IN_STRIDE 10 // x is (N, 10), we use first 9 cols
#define NH (Nn * Hh)
#define XS 128       // padded row stride for x-like (N,96) buffers
#define SLOTS 64     // CSR bucket capacity (Poisson(16) degree; P(>64) ~ 0)

__device__ __forceinline__ float sigf(float v) {
    return __builtin_amdgcn_rcpf(1.0f + __expf(-v));
}
__device__ __forceinline__ float tanhfast(float v) {
    float e = __expf(2.0f * v);
    return (e - 1.0f) * __builtin_amdgcn_rcpf(e + 1.0f);
}
__device__ __forceinline__ float leakyf(float v) {
    return v >= 0.0f ? v : 0.01f * v;
}

// ---------------- setup: transposes + Wf fold + init linear + zero deg -----
__global__ __launch_bounds__(256) void setup_kernel(
    const float* __restrict__ W_hh, const float* __restrict__ Wa1,
    const float* __restrict__ Wo1, const float* __restrict__ Wo2,
    const float* __restrict__ W_ggc, const float* __restrict__ W_ih,
    const float* __restrict__ x_in, const float* __restrict__ W_init,
    const float* __restrict__ b_init,
    float* __restrict__ Wt_hh, float* __restrict__ Wt_a1i,
    float* __restrict__ Wt_a1j, float* __restrict__ Wt_o1,
    float* __restrict__ Wt_o2, float* __restrict__ Wf,
    int* __restrict__ deg, float* __restrict__ xA)
{
    int gt = blockIdx.x * 256 + threadIdx.x;
    if (gt < Nn) deg[gt] = 0;
    if (gt < 64512) {   // transposes: Wt_hh 27648 + 4x9216
        int idx = gt;
        if (idx < 27648) {
            int k = idx / 288, c = idx % 288;
            Wt_hh[idx] = W_hh[c * 96 + k];
        } else if ((idx -= 27648) < 9216) {
            int k = idx / 96, h = idx % 96;
            Wt_a1i[idx] = Wa1[h * 192 + k];
        } else if ((idx -= 9216) < 9216) {
            int k = idx / 96, h = idx % 96;
            Wt_a1j[idx] = Wa1[h * 192 + 96 + k];
        } else if ((idx -= 9216) < 9216) {
            int k = idx / 96, j = idx % 96;
            Wt_o1[idx] = Wo1[j * 96 + k];
        } else {
            idx -= 9216;
            int k = idx / 96, j = idx % 96;
            Wt_o2[idx] = Wo2[j * 96 + k];
        }
    }
    if (gt < 27648) {   // Wf[k][c] = sum_j W_ggc[k][j] * W_ih[c][j]
        int k = gt / 288, c = gt % 288;
        const float* g = W_ggc + k * 96;
        const float* w = W_ih + c * 96;
        float acc = 0.0f;
        for (int j = 0; j < 96; ++j) acc += g[j] * w[j];
        Wf[gt] = acc;
    }
    if (gt < NH) {      // init linear
        int n = gt / Hh, j = gt - n * Hh;
        const float* xr = x_in + n * IN_STRIDE;
        const float* wr = W_init + j * IN_K;
        float acc = b_init[j];
#pragma unroll
        for (int k = 0; k < IN_K; ++k) acc += xr[k] * wr[k];
        xA[n * XS + j] = leakyf(acc);
    }
}

// ---------------- edges: CSR bucket scatter (needs zeroed deg) -------------
__global__ __launch_bounds__(256) void edges_kernel(
    const int* __restrict__ ei, int* __restrict__ deg, int* __restrict__ bucket)
{
    int e = blockIdx.x * 256 + threadIdx.x;
    if (e >= Ee) return;
    int src = ei[e];
    int tgt = ei[Ee + e];
    int slot = atomicAdd(&deg[tgt], 1);
    if (slot < SLOTS) bucket[tgt * SLOTS + slot] = src;
}

// ---------------- phase A: gather + GRU + attn projections (split-k) -------
// Block = 384 threads: half = tid/192, r = (tid/96)%2, h = tid%96.
// 2 rows/block, grid = 512.
__global__ __launch_bounds__(384) void gru_kernel(
    const float* __restrict__ xA, const int* __restrict__ deg,
    const int* __restrict__ bucket,
    const float* __restrict__ Wf, const float* __restrict__ Wt_hh,
    const float* __restrict__ b_ih, const float* __restrict__ b_hh,
    const float* __restrict__ Wt_a1i, const float* __restrict__ Wt_a1j,
    const float* __restrict__ ba1,
    float* __restrict__ xB, float* __restrict__ Ei, float* __restrict__ EjT)
{
    __shared__ float Pp[2][2][Hh];     // gather partials [half][r][h]
    __shared__ float Pm[2][Hh];        // combined mean [r][k]
    __shared__ float Xr[2][Hh];        // x row [r][k]
    __shared__ float Xo[2][Hh];        // GRU output row
    __shared__ float red6[2][2][Hh][6];// dot partials [half][r][h][gate]
    __shared__ float redp[2][2][Hh][2];// projection partials
    int tid = threadIdx.x;
    int half = tid / 192;
    int loc = tid - half * 192;
    int r = loc / Hh, h = loc - r * Hh;
    int n = blockIdx.x * 2 + r;
    // gather partial (slots strided by half) + x row load (half 0)
    {
        int d = deg[n];
        int dc = d < SLOTS ? d : SLOTS;
        const int* bk = bucket + n * SLOTS;
        float acc = 0.0f;
#pragma unroll 4
        for (int s = half; s < dc; s += 2)
            acc += xA[bk[s] * XS + h];
        Pp[half][r][h] = acc;
        if (half == 0) Xr[r][h] = xA[n * XS + h];
    }
    __syncthreads();
    if (half == 0) {
        float inv = __builtin_amdgcn_rcpf(fmaxf((float)deg[n], 1.0f));
        Pm[r][h] = (Pp[0][r][h] + Pp[1][r][h]) * inv;
    }
    __syncthreads();
    // GRU partial dots over this thread's k-half
    {
        const float* Pr = Pm[r];
        const float* xr = Xr[r];
        const float* pf = Wf + h;
        const float* ph = Wt_hh + h;
        float gir = 0.f, giz = 0.f, gin = 0.f;
        float ghr = 0.f, ghz = 0.f, ghn = 0.f;
        int k0 = half * 48;
#pragma unroll 4
        for (int k = k0; k < k0 + 48; ++k) {
            float a = Pr[k];
            float xv = xr[k];
            int o = k * 288;
            gir += a * pf[o];
            giz += a * pf[o + 96];
            gin += a * pf[o + 192];
            ghr += xv * ph[o];
            ghz += xv * ph[o + 96];
            ghn += xv * ph[o + 192];
        }
        red6[half][r][h][0] = gir;
        red6[half][r][h][1] = giz;
        red6[half][r][h][2] = gin;
        red6[half][r][h][3] = ghr;
        red6[half][r][h][4] = ghz;
        red6[half][r][h][5] = ghn;
    }
    __syncthreads();
    if (half == 0) {
        float gir = b_ih[h] + red6[0][r][h][0] + red6[1][r][h][0];
        float giz = b_ih[Hh + h] + red6[0][r][h][1] + red6[1][r][h][1];
        float gin = b_ih[2 * Hh + h] + red6[0][r][h][2] + red6[1][r][h][2];
        float ghr = b_hh[h] + red6[0][r][h][3] + red6[1][r][h][3];
        float ghz = b_hh[Hh + h] + red6[0][r][h][4] + red6[1][r][h][4];
        float ghn = b_hh[2 * Hh + h] + red6[0][r][h][5] + red6[1][r][h][5];
        float rr = sigf(gir + ghr);
        float z = sigf(giz + ghz);
        float nn2 = tanhfast(gin + rr * ghn);
        float xo = (1.0f - z) * nn2 + z * Xr[r][h];
        xB[n * XS + h] = xo;
        Xo[r][h] = xo;
    }
    __syncthreads();
    // attention projection partials
    {
        const float* row = Xo[r];
        const float* wi = Wt_a1i + h;
        const float* wj = Wt_a1j + h;
        float a = 0.0f, bb = 0.0f;
        int k0 = half * 48;
#pragma unroll 4
        for (int k = k0; k < k0 + 48; ++k) {
            float xv = row[k];
            a += xv * wi[k * 96];
            bb += xv * wj[k * 96];
        }
        redp[half][r][h][0] = a;
        redp[half][r][h][1] = bb;
    }
    __syncthreads();
    if (half == 0) {
        float a = redp[0][r][h][0] + redp[1][r][h][0];
        float bb = redp[0][r][h][1] + redp[1][r][h][1];
        Ei[n * Hh + h] = __expf(-(a + ba1[h]));
        EjT[h * Nn + n] = __expf(-bb);
    }
}

// ---------------- phase B: coeffs + row-GEMM, 4 rows x FULL j per block ----
// Grid = 256, 1024 threads (16 waves). Each thread owns ONE j for coeffs;
// one EjT load feeds all 4 rows. Rows complete in-block -> plain stores,
// and the output head can fuse into the final instance (HEAD=true).
// sm layout (floats): wa2 @0, eis @96 (4x96), C @480 (4x1024), red @4576
// (8x4x96 = 3072). HEAD reuses C space: xout @480, t1 @864, t2 @1248.
__global__ __launch_bounds__(1024) void attn_kernel_u0(
    const float* __restrict__ Ei, const float* __restrict__ EjT,
    const float* __restrict__ Wa2, const float* __restrict__ ba2,
    const int* __restrict__ adj, const float* __restrict__ xB,
    float* __restrict__ xOut)
{
    __shared__ float sm[7648];
    int tid = threadIdx.x;
    int i0 = blockIdx.x * 4;
    if (tid < Hh) sm[tid] = Wa2[tid];
    if (tid >= 128 && tid < 128 + 4 * Hh) {
        int t = tid - 128;
        int r = t / Hh, h = t - r * Hh;
        sm[96 + t] = Ei[(i0 + r) * Hh + h];
    }
    __syncthreads();
    // coeffs: thread owns j = tid
    {
        int j = tid;
        int m0 = adj[(i0 + 0) * Nn + j];
        int m1 = adj[(i0 + 1) * Nn + j];
        int m2 = adj[(i0 + 2) * Nn + j];
        int m3 = adj[(i0 + 3) * Nn + j];
        const float* e0 = sm + 96;
        float s0 = 0.f, s1 = 0.f, s2 = 0.f, s3 = 0.f;
#pragma unroll 4
        for (int k = 0; k < Hh; ++k) {
            float e = EjT[k * Nn + j];
            float wk = sm[k];
            s0 += __builtin_amdgcn_rcpf(fmaf(e0[k], e, 1.0f)) * wk;
            s1 += __builtin_amdgcn_rcpf(fmaf(e0[96 + k], e, 1.0f)) * wk;
            s2 += __builtin_amdgcn_rcpf(fmaf(e0[192 + k], e, 1.0f)) * wk;
            s3 += __builtin_amdgcn_rcpf(fmaf(e0[288 + k], e, 1.0f)) * wk;
        }
        float b2 = ba2[0];
        sm[480 + 0 * Nn + j] = (m0 == 1) ? sigf(s0 + b2) : 0.0f;
        sm[480 + 1 * Nn + j] = (m1 == 1) ? sigf(s1 + b2) : 0.0f;
        sm[480 + 2 * Nn + j] = (m2 == 1) ? sigf(s2 + b2) : 0.0f;
        sm[480 + 3 * Nn + j] = (m3 == 1) ? sigf(s3 + b2) : 0.0f;
    }
    __syncthreads();
    // row-GEMM: q = tid>>7 (8 j-octants of 128), h = tid&127
    {
        int q = tid >> 7;
        int h = tid & 127;
        if (h < Hh) {
            int jb = q * 128;
            const float* xc = xB + jb * XS + h;
            const float* c0 = sm + 480 + 0 * Nn + jb;
            const float* c1 = sm + 480 + 1 * Nn + jb;
            const float* c2 = sm + 480 + 2 * Nn + jb;
            const float* c3 = sm + 480 + 3 * Nn + jb;
            float a0 = 0.f, a1 = 0.f, a2 = 0.f, a3 = 0.f;
#pragma unroll 4
            for (int j = 0; j < 128; ++j) {
                float xv = xc[j * XS];
                a0 += c0[j] * xv;
                a1 += c1[j] * xv;
                a2 += c2[j] * xv;
                a3 += c3[j] * xv;
            }
            sm[4576 + ((q * 4 + 0) * Hh) + h] = a0;
            sm[4576 + ((q * 4 + 1) * Hh) + h] = a1;
            sm[4576 + ((q * 4 + 2) * Hh) + h] = a2;
            sm[4576 + ((q * 4 + 3) * Hh) + h] = a3;
        }
    }
    __syncthreads();
    if (tid < 4 * Hh) {
        int r = tid / Hh, h = tid - r * Hh;
        float v = 0.f;
#pragma unroll
        for (int q = 0; q < 8; ++q)
            v += sm[4576 + ((q * 4 + r) * Hh) + h];
        xOut[(i0 + r) * XS + h] = v;
    }
}

__global__ __launch_bounds__(1024) void attn_kernel_u1(
    const float* __restrict__ Ei, const float* __restrict__ EjT,
    const float* __restrict__ Wa2, const float* __restrict__ ba2,
    const int* __restrict__ adj, const float* __restrict__ xB,
    const float* __restrict__ Wt_o1, const float* __restrict__ bo1,
    const float* __restrict__ Wt_o2, const float* __restrict__ bo2,
    const float* __restrict__ Wp1, const float* __restrict__ bp1,
    const float* __restrict__ Wp2, const float* __restrict__ bp2,
    float* __restrict__ out)
{
    __shared__ float sm[7648];
    int tid = threadIdx.x;
    int i0 = blockIdx.x * 4;
    if (tid < Hh) sm[tid] = Wa2[tid];
    if (tid >= 128 && tid < 128 + 4 * Hh) {
        int t = tid - 128;
        int r = t / Hh, h = t - r * Hh;
        sm[96 + t] = Ei[(i0 + r) * Hh + h];
    }
    __syncthreads();
    {
        int j = tid;
        int m0 = adj[(i0 + 0) * Nn + j];
        int m1 = adj[(i0 + 1) * Nn + j];
        int m2 = adj[(i0 + 2) * Nn + j];
        int m3 = adj[(i0 + 3) * Nn + j];
        const float* e0 = sm + 96;
        float s0 = 0.f, s1 = 0.f, s2 = 0.f, s3 = 0.f;
#pragma unroll 4
        for (int k = 0; k < Hh; ++k) {
            float e = EjT[k * Nn + j];
            float wk = sm[k];
            s0 += __builtin_amdgcn_rcpf(fmaf(e0[k], e, 1.0f)) * wk;
            s1 += __builtin_amdgcn_rcpf(fmaf(e0[96 + k], e, 1.0f)) * wk;
            s2 += __builtin_amdgcn_rcpf(fmaf(e0[192 + k], e, 1.0f)) * wk;
            s3 += __builtin_amdgcn_rcpf(fmaf(e0[288 + k], e, 1.0f)) * wk;
        }
        float b2 = ba2[0];
        sm[480 + 0 * Nn + j] = (m0 == 1) ? sigf(s0 + b2) : 0.0f;
        sm[480 + 1 * Nn + j] = (m1 == 1) ? sigf(s1 + b2) : 0.0f;
        sm[480 + 2 * Nn + j] = (m2 == 1) ? sigf(s2 + b2) : 0.0f;
        sm[480 + 3 * Nn + j] = (m3 == 1) ? sigf(s3 + b2) : 0.0f;
    }
    __syncthreads();
    {
        int q = tid >> 7;
        int h = tid & 127;
        if (h < Hh) {
            int jb = q * 128;
            const float* xc = xB + jb * XS + h;
            const float* c0 = sm + 480 + 0 * Nn + jb;
            const float* c1 = sm + 480 + 1 * Nn + jb;
            const float* c2 = sm + 480 + 2 * Nn + jb;
            const float* c3 = sm + 480 + 3 * Nn + jb;
            float a0 = 0.f, a1 = 0.f, a2 = 0.f, a3 = 0.f;
#pragma unroll 4
            for (int j = 0; j < 128; ++j) {
                float xv = xc[j * XS];
                a0 += c0[j] * xv;
                a1 += c1[j] * xv;
                a2 += c2[j] * xv;
                a3 += c3[j] * xv;
            }
            sm[4576 + ((q * 4 + 0) * Hh) + h] = a0;
            sm[4576 + ((q * 4 + 1) * Hh) + h] = a1;
            sm[4576 + ((q * 4 + 2) * Hh) + h] = a2;
            sm[4576 + ((q * 4 + 3) * Hh) + h] = a3;
        }
    }
    __syncthreads();
    // xout rows (reuse C space @480)
    if (tid < 4 * Hh) {
        int r = tid / Hh, h = tid - r * Hh;
        float v = 0.f;
#pragma unroll
        for (int q = 0; q < 8; ++q)
            v += sm[4576 + ((q * 4 + r) * Hh) + h];
        sm[480 + r * Hh + h] = v;
    }
    __syncthreads();
    // head: t1 = leaky(xout @ Wo1.T + bo1)  (@864)
    if (tid < 4 * Hh) {
        int r = tid / Hh, h = tid - r * Hh;
        const float* w = Wt_o1 + h;
        const float* xr = sm + 480 + r * Hh;
        float acc = bo1[h];
        for (int k = 0; k < Hh; ++k) acc += xr[k] * w[k * 96];
        sm[864 + r * Hh + h] = leakyf(acc);
    }
    __syncthreads();
    // t2 = leaky(t1 @ Wo2.T + bo2)  (@1248)
    if (tid < 4 * Hh) {
        int r = tid / Hh, h = tid - r * Hh;
        const float* w = Wt_o2 + h;
        const float* xr = sm + 864 + r * Hh;
        float acc = bo2[h];
        for (int k = 0; k < Hh; ++k) acc += xr[k] * w[k * 96];
        sm[1248 + r * Hh + h] = leakyf(acc);
    }
    __syncthreads();
    if (tid < 8) {
        int r = tid >> 1, which = tid & 1;
        const float* wp = which ? Wp2 : Wp1;
        const float* xr = sm + 1248 + r * Hh;
        float acc = 0.f;
        for (int k = 0; k < Hh; ++k) acc += xr[k] * wp[k];
        float b = which ? bp2[0] : bp1[0];
        out[which * Nn + i0 + r] = sigf(acc + b);
    }
}

extern "C" void kernel_launch(void* const* d_in, const int* in_sizes, int n_in,
                              void* d_out, int out_size, void* d_ws, size_t ws_size,
                              hipStream_t stream)
{
    const float* x_in   = (const float*)d_in[0];
    const int*   ei     = (const int*)d_in[1];
    const int*   adj    = (const int*)d_in[2];
    const float* W_init = (const float*)d_in[3];
    const float* b_init = (const float*)d_in[4];
    const float* W_ggc  = (const float*)d_in[5];
    const float* W_ih   = (const float*)d_in[6];
    const float* W_hh   = (const float*)d_in[7];
    const float* b_ih   = (const float*)d_in[8];
    const float* b_hh   = (const float*)d_in[9];
    const float* Wa1    = (const float*)d_in[10];
    const float* ba1    = (const float*)d_in[11];
    const float* Wa2    = (const float*)d_in[12];
    const float* ba2    = (const float*)d_in[13];
    const float* Wo1    = (const float*)d_in[14];
    const float* bo1    = (const float*)d_in[15];
    const float* Wo2    = (const float*)d_in[16];
    const float* bo2    = (const float*)d_in[17];
    const float* Wp1    = (const float*)d_in[18];
    const float* bp1    = (const float*)d_in[19];
    const float* Wp2    = (const float*)d_in[20];
    const float* bp2    = (const float*)d_in[21];
    float* out = (float*)d_out;

    // workspace layout, ~2.5 MB
    float* ws     = (float*)d_ws;
    float* xA     = ws;                     // (N, XS)
    float* xB     = xA + Nn * XS;           // (N, XS)
    float* xC     = xB + Nn * XS;           // (N, XS)
    float* Ei     = xC + Nn * XS;           // (N, 96)
    float* EjT    = Ei + NH;                // (96, N)
    float* Wt_hh  = EjT + NH;               // 96*288
    float* Wf     = Wt_hh + 27648;          // 96*288
    float* Wt_a1i = Wf + 27648;             // 96*96
    float* Wt_a1j = Wt_a1i + 9216;
    float* Wt_o1  = Wt_a1j + 9216;
    float* Wt_o2  = Wt_o1 + 9216;
    int*   deg    = (int*)(Wt_o2 + 9216);   // (N)
    int*   bucket = deg + Nn;               // (N, SLOTS)

    setup_kernel<<<(NH + 255) / 256, 256, 0, stream>>>(
        W_hh, Wa1, Wo1, Wo2, W_ggc, W_ih, x_in, W_init, b_init,
        Wt_hh, Wt_a1i, Wt_a1j, Wt_o1, Wt_o2, Wf, deg, xA);
    edges_kernel<<<(Ee + 255) / 256, 256, 0, stream>>>(ei, deg, bucket);

    // unroll 0: xA -> xB -> xC
    gru_kernel<<<Nn / 2, 384, 0, stream>>>(
        xA, deg, bucket, Wf, Wt_hh, b_ih, b_hh, Wt_a1i, Wt_a1j, ba1,
        xB, Ei, EjT);
    attn_kernel_u0<<<Nn / 4, 1024, 0, stream>>>(
        Ei, EjT, Wa2, ba2, adj, xB, xC);
    // unroll 1: xC -> xB -> (head fused) -> out
    gru_kernel<<<Nn / 2, 384, 0, stream>>>(
        xC, deg, bucket, Wf, Wt_hh, b_ih, b_hh, Wt_a1i, Wt_a1j, ba1,
        xB, Ei, EjT);
    attn_kernel_u1<<<Nn / 4, 1024, 0, stream>>>(
        Ei, EjT, Wa2, ba2, adj, xB,
        Wt_o1, bo1, Wt_o2, bo2, Wp1, bp1, Wp2, bp2, out);
}

// Round 10
// 191.937 us; speedup vs baseline: 4.7199x; 1.0271x over previous
//
#include <hip/hip_runtime.h>

// Problem constants (from reference)
#define Nn 1024
#define Hh 96
#define Ee 16384
#define IN_K 9       // IN_RAW-1
#define IN_STRIDE 10 // x is (N, 10), we use first 9 cols
#define NH (Nn * Hh)
#define XS 128       // padded row stride for x-like (N,96) buffers
#define SLOTS 64     // CSR bucket capacity (Poisson(16) degree; P(>64) ~ 0)

__device__ __forceinline__ float sigf(float v) {
    return __builtin_amdgcn_rcpf(1.0f + __expf(-v));
}
__device__ __forceinline__ float tanhfast(float v) {
    float e = __expf(2.0f * v);
    return (e - 1.0f) * __builtin_amdgcn_rcpf(e + 1.0f);
}
__device__ __forceinline__ float leakyf(float v) {
    return v >= 0.0f ? v : 0.01f * v;
}

// ---------------- setup: transposes + Wf fold + init linear + zero deg -----
__global__ __launch_bounds__(256) void setup_kernel(
    const float* __restrict__ W_hh, const float* __restrict__ Wa1,
    const float* __restrict__ Wo1, const float* __restrict__ Wo2,
    const float* __restrict__ W_ggc, const float* __restrict__ W_ih,
    const float* __restrict__ x_in, const float* __restrict__ W_init,
    const float* __restrict__ b_init,
    float* __restrict__ Wt_hh, float* __restrict__ Wt_a1i,
    float* __restrict__ Wt_a1j, float* __restrict__ Wt_o1,
    float* __restrict__ Wt_o2, float* __restrict__ Wf,
    int* __restrict__ deg, float* __restrict__ xA)
{
    int gt = blockIdx.x * 256 + threadIdx.x;
    if (gt < Nn) deg[gt] = 0;
    if (gt < 64512) {   // transposes: Wt_hh 27648 + 4x9216
        int idx = gt;
        if (idx < 27648) {
            int k = idx / 288, c = idx % 288;
            Wt_hh[idx] = W_hh[c * 96 + k];
        } else if ((idx -= 27648) < 9216) {
            int k = idx / 96, h = idx % 96;
            Wt_a1i[idx] = Wa1[h * 192 + k];
        } else if ((idx -= 9216) < 9216) {
            int k = idx / 96, h = idx % 96;
            Wt_a1j[idx] = Wa1[h * 192 + 96 + k];
        } else if ((idx -= 9216) < 9216) {
            int k = idx / 96, j = idx % 96;
            Wt_o1[idx] = Wo1[j * 96 + k];
        } else {
            idx -= 9216;
            int k = idx / 96, j = idx % 96;
            Wt_o2[idx] = Wo2[j * 96 + k];
        }
    }
    if (gt < 27648) {   // Wf[k][c] = sum_j W_ggc[k][j] * W_ih[c][j]
        int k = gt / 288, c = gt % 288;
        const float* g = W_ggc + k * 96;
        const float* w = W_ih + c * 96;
        float acc = 0.0f;
        for (int j = 0; j < 96; ++j) acc += g[j] * w[j];
        Wf[gt] = acc;
    }
    if (gt < NH) {      // init linear
        int n = gt / Hh, j = gt - n * Hh;
        const float* xr = x_in + n * IN_STRIDE;
        const float* wr = W_init + j * IN_K;
        float acc = b_init[j];
#pragma unroll
        for (int k = 0; k < IN_K; ++k) acc += xr[k] * wr[k];
        xA[n * XS + j] = leakyf(acc);
    }
}

// ---------------- edges: CSR bucket scatter (needs zeroed deg) -------------
__global__ __launch_bounds__(256) void edges_kernel(
    const int* __restrict__ ei, int* __restrict__ deg, int* __restrict__ bucket)
{
    int e = blockIdx.x * 256 + threadIdx.x;
    if (e >= Ee) return;
    int src = ei[e];
    int tgt = ei[Ee + e];
    int slot = atomicAdd(&deg[tgt], 1);
    if (slot < SLOTS) bucket[tgt * SLOTS + slot] = src;
}

// ---------------- phase A: gather + GRU + attn projections (split-k) -------
// Block = 384 threads: half = tid/192, r = (tid/96)%2, h = tid%96.
// 2 rows/block, grid = 512.
__global__ __launch_bounds__(384) void gru_kernel(
    const float* __restrict__ xA, const int* __restrict__ deg,
    const int* __restrict__ bucket,
    const float* __restrict__ Wf, const float* __restrict__ Wt_hh,
    const float* __restrict__ b_ih, const float* __restrict__ b_hh,
    const float* __restrict__ Wt_a1i, const float* __restrict__ Wt_a1j,
    const float* __restrict__ ba1,
    float* __restrict__ xB, float* __restrict__ Ei, float* __restrict__ EjT)
{
    __shared__ float Pp[2][2][Hh];     // gather partials [half][r][h]
    __shared__ float Pm[2][Hh];        // combined mean [r][k]
    __shared__ float Xr[2][Hh];        // x row [r][k]
    __shared__ float Xo[2][Hh];        // GRU output row
    __shared__ float red6[2][2][Hh][6];// dot partials [half][r][h][gate]
    __shared__ float redp[2][2][Hh][2];// projection partials
    int tid = threadIdx.x;
    int half = tid / 192;
    int loc = tid - half * 192;
    int r = loc / Hh, h = loc - r * Hh;
    int n = blockIdx.x * 2 + r;
    // gather partial (slots strided by half) + x row load (half 0)
    {
        int d = deg[n];
        int dc = d < SLOTS ? d : SLOTS;
        const int* bk = bucket + n * SLOTS;
        float acc = 0.0f;
#pragma unroll 4
        for (int s = half; s < dc; s += 2)
            acc += xA[bk[s] * XS + h];
        Pp[half][r][h] = acc;
        if (half == 0) Xr[r][h] = xA[n * XS + h];
    }
    __syncthreads();
    if (half == 0) {
        float inv = __builtin_amdgcn_rcpf(fmaxf((float)deg[n], 1.0f));
        Pm[r][h] = (Pp[0][r][h] + Pp[1][r][h]) * inv;
    }
    __syncthreads();
    // GRU partial dots over this thread's k-half
    {
        const float* Pr = Pm[r];
        const float* xr = Xr[r];
        const float* pf = Wf + h;
        const float* ph = Wt_hh + h;
        float gir = 0.f, giz = 0.f, gin = 0.f;
        float ghr = 0.f, ghz = 0.f, ghn = 0.f;
        int k0 = half * 48;
#pragma unroll 4
        for (int k = k0; k < k0 + 48; ++k) {
            float a = Pr[k];
            float xv = xr[k];
            int o = k * 288;
            gir += a * pf[o];
            giz += a * pf[o + 96];
            gin += a * pf[o + 192];
            ghr += xv * ph[o];
            ghz += xv * ph[o + 96];
            ghn += xv * ph[o + 192];
        }
        red6[half][r][h][0] = gir;
        red6[half][r][h][1] = giz;
        red6[half][r][h][2] = gin;
        red6[half][r][h][3] = ghr;
        red6[half][r][h][4] = ghz;
        red6[half][r][h][5] = ghn;
    }
    __syncthreads();
    if (half == 0) {
        float gir = b_ih[h] + red6[0][r][h][0] + red6[1][r][h][0];
        float giz = b_ih[Hh + h] + red6[0][r][h][1] + red6[1][r][h][1];
        float gin = b_ih[2 * Hh + h] + red6[0][r][h][2] + red6[1][r][h][2];
        float ghr = b_hh[h] + red6[0][r][h][3] + red6[1][r][h][3];
        float ghz = b_hh[Hh + h] + red6[0][r][h][4] + red6[1][r][h][4];
        float ghn = b_hh[2 * Hh + h] + red6[0][r][h][5] + red6[1][r][h][5];
        float rr = sigf(gir + ghr);
        float z = sigf(giz + ghz);
        float nn2 = tanhfast(gin + rr * ghn);
        float xo = (1.0f - z) * nn2 + z * Xr[r][h];
        xB[n * XS + h] = xo;
        Xo[r][h] = xo;
    }
    __syncthreads();
    // attention projection partials
    {
        const float* row = Xo[r];
        const float* wi = Wt_a1i + h;
        const float* wj = Wt_a1j + h;
        float a = 0.0f, bb = 0.0f;
        int k0 = half * 48;
#pragma unroll 4
        for (int k = k0; k < k0 + 48; ++k) {
            float xv = row[k];
            a += xv * wi[k * 96];
            bb += xv * wj[k * 96];
        }
        redp[half][r][h][0] = a;
        redp[half][r][h][1] = bb;
    }
    __syncthreads();
    if (half == 0) {
        float a = redp[0][r][h][0] + redp[1][r][h][0];
        float bb = redp[0][r][h][1] + redp[1][r][h][1];
        Ei[n * Hh + h] = __expf(-(a + ba1[h]));
        EjT[h * Nn + n] = __expf(-bb);
    }
}

// ---------------- phase B: coeffs + row-GEMM, 4 rows x FULL j per block ----
// Grid = 256, 1024 threads. Thread owns ONE j; one EjT vector load per k
// feeds all 4 rows. Ei/Wa2 are read with WAVE-UNIFORM indices directly from
// global -> compiler emits s_load (scalar cache), keeping the vector-memory
// path free for EjT. No LDS staging, no pre-loop barrier.
// sm layout (floats): C @0 (4x1024), red @4096 (8x4x96=3072) = 28.7 KB.
__global__ __launch_bounds__(1024) void attn_kernel_u0(
    const float* __restrict__ Ei, const float* __restrict__ EjT,
    const float* __restrict__ Wa2, const float* __restrict__ ba2,
    const int* __restrict__ adj, const float* __restrict__ xB,
    float* __restrict__ xOut)
{
    __shared__ float sm[7168];
    int tid = threadIdx.x;
    int i0 = blockIdx.x * 4;
    // coeffs: thread owns j = tid; Ei/Wa2 via uniform scalar loads
    {
        int j = tid;
        int m0 = adj[(i0 + 0) * Nn + j];
        int m1 = adj[(i0 + 1) * Nn + j];
        int m2 = adj[(i0 + 2) * Nn + j];
        int m3 = adj[(i0 + 3) * Nn + j];
        const float* e0 = Ei + i0 * Hh;       // uniform base
        float s0 = 0.f, s1 = 0.f, s2 = 0.f, s3 = 0.f;
#pragma unroll 8
        for (int k = 0; k < Hh; ++k) {
            float e = EjT[k * Nn + j];
            float wk = Wa2[k];                 // s_load
            s0 += __builtin_amdgcn_rcpf(fmaf(e0[k], e, 1.0f)) * wk;
            s1 += __builtin_amdgcn_rcpf(fmaf(e0[96 + k], e, 1.0f)) * wk;
            s2 += __builtin_amdgcn_rcpf(fmaf(e0[192 + k], e, 1.0f)) * wk;
            s3 += __builtin_amdgcn_rcpf(fmaf(e0[288 + k], e, 1.0f)) * wk;
        }
        float b2 = ba2[0];
        sm[0 * Nn + j] = (m0 == 1) ? sigf(s0 + b2) : 0.0f;
        sm[1 * Nn + j] = (m1 == 1) ? sigf(s1 + b2) : 0.0f;
        sm[2 * Nn + j] = (m2 == 1) ? sigf(s2 + b2) : 0.0f;
        sm[3 * Nn + j] = (m3 == 1) ? sigf(s3 + b2) : 0.0f;
    }
    __syncthreads();
    // row-GEMM: q = tid>>7 (8 j-octants of 128), h = tid&127
    {
        int q = tid >> 7;
        int h = tid & 127;
        if (h < Hh) {
            int jb = q * 128;
            const float* xc = xB + jb * XS + h;
            const float* c0 = sm + 0 * Nn + jb;
            const float* c1 = sm + 1 * Nn + jb;
            const float* c2 = sm + 2 * Nn + jb;
            const float* c3 = sm + 3 * Nn + jb;
            float a0 = 0.f, a1 = 0.f, a2 = 0.f, a3 = 0.f;
#pragma unroll 4
            for (int j = 0; j < 128; ++j) {
                float xv = xc[j * XS];
                a0 += c0[j] * xv;
                a1 += c1[j] * xv;
                a2 += c2[j] * xv;
                a3 += c3[j] * xv;
            }
            sm[4096 + ((q * 4 + 0) * Hh) + h] = a0;
            sm[4096 + ((q * 4 + 1) * Hh) + h] = a1;
            sm[4096 + ((q * 4 + 2) * Hh) + h] = a2;
            sm[4096 + ((q * 4 + 3) * Hh) + h] = a3;
        }
    }
    __syncthreads();
    if (tid < 4 * Hh) {
        int r = tid / Hh, h = tid - r * Hh;
        float v = 0.f;
#pragma unroll
        for (int q = 0; q < 8; ++q)
            v += sm[4096 + ((q * 4 + r) * Hh) + h];
        xOut[(i0 + r) * XS + h] = v;
    }
}

__global__ __launch_bounds__(1024) void attn_kernel_u1(
    const float* __restrict__ Ei, const float* __restrict__ EjT,
    const float* __restrict__ Wa2, const float* __restrict__ ba2,
    const int* __restrict__ adj, const float* __restrict__ xB,
    const float* __restrict__ Wt_o1, const float* __restrict__ bo1,
    const float* __restrict__ Wt_o2, const float* __restrict__ bo2,
    const float* __restrict__ Wp1, const float* __restrict__ bp1,
    const float* __restrict__ Wp2, const float* __restrict__ bp2,
    float* __restrict__ out)
{
    __shared__ float sm[7168];
    __shared__ float hd[3][4][Hh];    // xout, t1, t2 for the fused head
    int tid = threadIdx.x;
    int i0 = blockIdx.x * 4;
    {
        int j = tid;
        int m0 = adj[(i0 + 0) * Nn + j];
        int m1 = adj[(i0 + 1) * Nn + j];
        int m2 = adj[(i0 + 2) * Nn + j];
        int m3 = adj[(i0 + 3) * Nn + j];
        const float* e0 = Ei + i0 * Hh;
        float s0 = 0.f, s1 = 0.f, s2 = 0.f, s3 = 0.f;
#pragma unroll 8
        for (int k = 0; k < Hh; ++k) {
            float e = EjT[k * Nn + j];
            float wk = Wa2[k];
            s0 += __builtin_amdgcn_rcpf(fmaf(e0[k], e, 1.0f)) * wk;
            s1 += __builtin_amdgcn_rcpf(fmaf(e0[96 + k], e, 1.0f)) * wk;
            s2 += __builtin_amdgcn_rcpf(fmaf(e0[192 + k], e, 1.0f)) * wk;
            s3 += __builtin_amdgcn_rcpf(fmaf(e0[288 + k], e, 1.0f)) * wk;
        }
        float b2 = ba2[0];
        sm[0 * Nn + j] = (m0 == 1) ? sigf(s0 + b2) : 0.0f;
        sm[1 * Nn + j] = (m1 == 1) ? sigf(s1 + b2) : 0.0f;
        sm[2 * Nn + j] = (m2 == 1) ? sigf(s2 + b2) : 0.0f;
        sm[3 * Nn + j] = (m3 == 1) ? sigf(s3 + b2) : 0.0f;
    }
    __syncthreads();
    {
        int q = tid >> 7;
        int h = tid & 127;
        if (h < Hh) {
            int jb = q * 128;
            const float* xc = xB + jb * XS + h;
            const float* c0 = sm + 0 * Nn + jb;
            const float* c1 = sm + 1 * Nn + jb;
            const float* c2 = sm + 2 * Nn + jb;
            const float* c3 = sm + 3 * Nn + jb;
            float a0 = 0.f, a1 = 0.f, a2 = 0.f, a3 = 0.f;
#pragma unroll 4
            for (int j = 0; j < 128; ++j) {
                float xv = xc[j * XS];
                a0 += c0[j] * xv;
                a1 += c1[j] * xv;
                a2 += c2[j] * xv;
                a3 += c3[j] * xv;
            }
            sm[4096 + ((q * 4 + 0) * Hh) + h] = a0;
            sm[4096 + ((q * 4 + 1) * Hh) + h] = a1;
            sm[4096 + ((q * 4 + 2) * Hh) + h] = a2;
            sm[4096 + ((q * 4 + 3) * Hh) + h] = a3;
        }
    }
    __syncthreads();
    if (tid < 4 * Hh) {
        int r = tid / Hh, h = tid - r * Hh;
        float v = 0.f;
#pragma unroll
        for (int q = 0; q < 8; ++q)
            v += sm[4096 + ((q * 4 + r) * Hh) + h];
        hd[0][r][h] = v;
    }
    __syncthreads();
    // head: t1 = leaky(xout @ Wo1.T + bo1)
    if (tid < 4 * Hh) {
        int r = tid / Hh, h = tid - r * Hh;
        const float* w = Wt_o1 + h;
        const float* xr = hd[0][r];
        float acc = bo1[h];
        for (int k = 0; k < Hh; ++k) acc += xr[k] * w[k * 96];
        hd[1][r][h] = leakyf(acc);
    }
    __syncthreads();
    if (tid < 4 * Hh) {
        int r = tid / Hh, h = tid - r * Hh;
        const float* w = Wt_o2 + h;
        const float* xr = hd[1][r];
        float acc = bo2[h];
        for (int k = 0; k < Hh; ++k) acc += xr[k] * w[k * 96];
        hd[2][r][h] = leakyf(acc);
    }
    __syncthreads();
    if (tid < 8) {
        int r = tid >> 1, which = tid & 1;
        const float* wp = which ? Wp2 : Wp1;
        const float* xr = hd[2][r];
        float acc = 0.f;
        for (int k = 0; k < Hh; ++k) acc += xr[k] * wp[k];
        float b = which ? bp2[0] : bp1[0];
        out[which * Nn + i0 + r] = sigf(acc + b);
    }
}

extern "C" void kernel_launch(void* const* d_in, const int* in_sizes, int n_in,
                              void* d_out, int out_size, void* d_ws, size_t ws_size,
                              hipStream_t stream)
{
    const float* x_in   = (const float*)d_in[0];
    const int*   ei     = (const int*)d_in[1];
    const int*   adj    = (const int*)d_in[2];
    const float* W_init = (const float*)d_in[3];
    const float* b_init = (const float*)d_in[4];
    const float* W_ggc  = (const float*)d_in[5];
    const float* W_ih   = (const float*)d_in[6];
    const float* W_hh   = (const float*)d_in[7];
    const float* b_ih   = (const float*)d_in[8];
    const float* b_hh   = (const float*)d_in[9];
    const float* Wa1    = (const float*)d_in[10];
    const float* ba1    = (const float*)d_in[11];
    const float* Wa2    = (const float*)d_in[12];
    const float* ba2    = (const float*)d_in[13];
    const float* Wo1    = (const float*)d_in[14];
    const float* bo1    = (const float*)d_in[15];
    const float* Wo2    = (const float*)d_in[16];
    const float* bo2    = (const float*)d_in[17];
    const float* Wp1    = (const float*)d_in[18];
    const float* bp1    = (const float*)d_in[19];
    const float* Wp2    = (const float*)d_in[20];
    const float* bp2    = (const float*)d_in[21];
    float* out = (float*)d_out;

    // workspace layout, ~2.5 MB
    float* ws     = (float*)d_ws;
    float* xA     = ws;                     // (N, XS)
    float* xB     = xA + Nn * XS;           // (N, XS)
    float* xC     = xB + Nn * XS;           // (N, XS)
    float* Ei     = xC + Nn * XS;           // (N, 96)
    float* EjT    = Ei + NH;                // (96, N)
    float* Wt_hh  = EjT + NH;               // 96*288
    float* Wf     = Wt_hh + 27648;          // 96*288
    float* Wt_a1i = Wf + 27648;             // 96*96
    float* Wt_a1j = Wt_a1i + 9216;
    float* Wt_o1  = Wt_a1j + 9216;
    float* Wt_o2  = Wt_o1 + 9216;
    int*   deg    = (int*)(Wt_o2 + 9216);   // (N)
    int*   bucket = deg + Nn;               // (N, SLOTS)

    setup_kernel<<<(NH + 255) / 256, 256, 0, stream>>>(
        W_hh, Wa1, Wo1, Wo2, W_ggc, W_ih, x_in, W_init, b_init,
        Wt_hh, Wt_a1i, Wt_a1j, Wt_o1, Wt_o2, Wf, deg, xA);
    edges_kernel<<<(Ee + 255) / 256, 256, 0, stream>>>(ei, deg, bucket);

    // unroll 0: xA -> xB -> xC
    gru_kernel<<<Nn / 2, 384, 0, stream>>>(
        xA, deg, bucket, Wf, Wt_hh, b_ih, b_hh, Wt_a1i, Wt_a1j, ba1,
        xB, Ei, EjT);
    attn_kernel_u0<<<Nn / 4, 1024, 0, stream>>>(
        Ei, EjT, Wa2, ba2, adj, xB, xC);
    // unroll 1: xC -> xB -> (head fused) -> out
    gru_kernel<<<Nn / 2, 384, 0, stream>>>(
        xC, deg, bucket, Wf, Wt_hh, b_ih, b_hh, Wt_a1i, Wt_a1j, ba1,
        xB, Ei, EjT);
    attn_kernel_u1<<<Nn / 4, 1024, 0, stream>>>(
        Ei, EjT, Wa2, ba2, adj, xB,
        Wt_o1, bo1, Wt_o2, bo2, Wp1, bp1, Wp2, bp2, out);
}

// Round 11
// 189.732 us; speedup vs baseline: 4.7747x; 1.0116x over previous
//
#include <hip/hip_runtime.h>

// Problem constants (from reference)
#define Nn 1024
#define Hh 96
#define Ee 16384
#define IN_K 9       // IN_RAW-1
#define IN_STRIDE 10 // x is (N, 10), we use first 9 cols
#define NH (Nn * Hh)
#define XS 128       // padded row stride for x-like (N,96) buffers
#define SLOTS 64     // CSR bucket capacity (Poisson(16) degree; P(>64) ~ 0)

__device__ __forceinline__ float sigf(float v) {
    return __builtin_amdgcn_rcpf(1.0f + __expf(-v));
}
__device__ __forceinline__ float tanhfast(float v) {
    float e = __expf(2.0f * v);
    return (e - 1.0f) * __builtin_amdgcn_rcpf(e + 1.0f);
}
__device__ __forceinline__ float leakyf(float v) {
    return v >= 0.0f ? v : 0.01f * v;
}

// ---------------- setup: transposes + Wf fold + init linear + zero deg -----
__global__ __launch_bounds__(256) void setup_kernel(
    const float* __restrict__ W_hh, const float* __restrict__ Wa1,
    const float* __restrict__ Wo1, const float* __restrict__ Wo2,
    const float* __restrict__ W_ggc, const float* __restrict__ W_ih,
    const float* __restrict__ x_in, const float* __restrict__ W_init,
    const float* __restrict__ b_init,
    float* __restrict__ Wt_hh, float* __restrict__ Wt_a1i,
    float* __restrict__ Wt_a1j, float* __restrict__ Wt_o1,
    float* __restrict__ Wt_o2, float* __restrict__ Wf,
    int* __restrict__ deg, float* __restrict__ xA)
{
    int gt = blockIdx.x * 256 + threadIdx.x;
    if (gt < Nn) deg[gt] = 0;
    if (gt < 64512) {   // transposes: Wt_hh 27648 + 4x9216
        int idx = gt;
        if (idx < 27648) {
            int k = idx / 288, c = idx % 288;
            Wt_hh[idx] = W_hh[c * 96 + k];
        } else if ((idx -= 27648) < 9216) {
            int k = idx / 96, h = idx % 96;
            Wt_a1i[idx] = Wa1[h * 192 + k];
        } else if ((idx -= 9216) < 9216) {
            int k = idx / 96, h = idx % 96;
            Wt_a1j[idx] = Wa1[h * 192 + 96 + k];
        } else if ((idx -= 9216) < 9216) {
            int k = idx / 96, j = idx % 96;
            Wt_o1[idx] = Wo1[j * 96 + k];
        } else {
            idx -= 9216;
            int k = idx / 96, j = idx % 96;
            Wt_o2[idx] = Wo2[j * 96 + k];
        }
    }
    if (gt < 27648) {   // Wf[k][c] = sum_j W_ggc[k][j] * W_ih[c][j]
        int k = gt / 288, c = gt % 288;
        const float* g = W_ggc + k * 96;
        const float* w = W_ih + c * 96;
        float acc = 0.0f;
        for (int j = 0; j < 96; ++j) acc += g[j] * w[j];
        Wf[gt] = acc;
    }
    if (gt < NH) {      // init linear
        int n = gt / Hh, j = gt - n * Hh;
        const float* xr = x_in + n * IN_STRIDE;
        const float* wr = W_init + j * IN_K;
        float acc = b_init[j];
#pragma unroll
        for (int k = 0; k < IN_K; ++k) acc += xr[k] * wr[k];
        xA[n * XS + j] = leakyf(acc);
    }
}

// ---------------- edges: CSR bucket scatter (needs zeroed deg) -------------
__global__ __launch_bounds__(256) void edges_kernel(
    const int* __restrict__ ei, int* __restrict__ deg, int* __restrict__ bucket)
{
    int e = blockIdx.x * 256 + threadIdx.x;
    if (e >= Ee) return;
    int src = ei[e];
    int tgt = ei[Ee + e];
    int slot = atomicAdd(&deg[tgt], 1);
    if (slot < SLOTS) bucket[tgt * SLOTS + slot] = src;
}

// ---------------- phase A: gather + GRU + attn projections -----------------
// 1 row/block, 384 threads = 4 k-quarters (q) x 96 h. Grid = 1024 ->
// 4 blocks/CU (24 waves/CU) for latency hiding. LDS ~15 KB.
__global__ __launch_bounds__(384, 4) void gru_kernel(
    const float* __restrict__ xA, const int* __restrict__ deg,
    const int* __restrict__ bucket,
    const float* __restrict__ Wf, const float* __restrict__ Wt_hh,
    const float* __restrict__ b_ih, const float* __restrict__ b_hh,
    const float* __restrict__ Wt_a1i, const float* __restrict__ Wt_a1j,
    const float* __restrict__ ba1,
    float* __restrict__ xB, float* __restrict__ Ei, float* __restrict__ EjT)
{
    __shared__ float Pq[4][Hh];        // gather partials per quarter
    __shared__ float Pm[Hh];           // combined mean
    __shared__ float Xr[Hh];           // x row
    __shared__ float Xo[Hh];           // GRU output row
    __shared__ float red6[4][Hh][6];   // gate dot partials [q][h][gate]
    __shared__ float redp[4][Hh][2];   // projection partials
    int tid = threadIdx.x;
    int q = tid / Hh;                  // 0..3
    int h = tid - q * Hh;
    int n = blockIdx.x;
    // gather partial: quarter q sums slots q, q+4, ... (bk[s] is wave-uniform)
    {
        int d = deg[n];
        int dc = d < SLOTS ? d : SLOTS;
        const int* bk = bucket + n * SLOTS;
        float acc = 0.0f;
        for (int s = q; s < dc; s += 4)
            acc += xA[bk[s] * XS + h];
        Pq[q][h] = acc;
        if (q == 0) Xr[h] = xA[n * XS + h];
    }
    __syncthreads();
    if (q == 0) {
        float inv = __builtin_amdgcn_rcpf(fmaxf((float)deg[n], 1.0f));
        Pm[h] = (Pq[0][h] + Pq[1][h] + Pq[2][h] + Pq[3][h]) * inv;
    }
    __syncthreads();
    // GRU partial dots over this thread's k-quarter (24 k)
    {
        const float* pf = Wf + h;
        const float* ph = Wt_hh + h;
        float gir = 0.f, giz = 0.f, gin = 0.f;
        float ghr = 0.f, ghz = 0.f, ghn = 0.f;
        int k0 = q * 24;
#pragma unroll 4
        for (int k = k0; k < k0 + 24; ++k) {
            float a = Pm[k];      // LDS broadcast
            float xv = Xr[k];     // LDS broadcast
            int o = k * 288;
            gir += a * pf[o];
            giz += a * pf[o + 96];
            gin += a * pf[o + 192];
            ghr += xv * ph[o];
            ghz += xv * ph[o + 96];
            ghn += xv * ph[o + 192];
        }
        red6[q][h][0] = gir;
        red6[q][h][1] = giz;
        red6[q][h][2] = gin;
        red6[q][h][3] = ghr;
        red6[q][h][4] = ghz;
        red6[q][h][5] = ghn;
    }
    __syncthreads();
    if (q == 0) {
        float gir = b_ih[h], giz = b_ih[Hh + h], gin = b_ih[2 * Hh + h];
        float ghr = b_hh[h], ghz = b_hh[Hh + h], ghn = b_hh[2 * Hh + h];
#pragma unroll
        for (int qq = 0; qq < 4; ++qq) {
            gir += red6[qq][h][0];
            giz += red6[qq][h][1];
            gin += red6[qq][h][2];
            ghr += red6[qq][h][3];
            ghz += red6[qq][h][4];
            ghn += red6[qq][h][5];
        }
        float rr = sigf(gir + ghr);
        float z = sigf(giz + ghz);
        float nn2 = tanhfast(gin + rr * ghn);
        float xo = (1.0f - z) * nn2 + z * Xr[h];
        xB[n * XS + h] = xo;
        Xo[h] = xo;
    }
    __syncthreads();
    // attention projection partials (24 k per thread)
    {
        const float* wi = Wt_a1i + h;
        const float* wj = Wt_a1j + h;
        float a = 0.0f, bb = 0.0f;
        int k0 = q * 24;
#pragma unroll 4
        for (int k = k0; k < k0 + 24; ++k) {
            float xv = Xo[k];     // LDS broadcast
            a += xv * wi[k * 96];
            bb += xv * wj[k * 96];
        }
        redp[q][h][0] = a;
        redp[q][h][1] = bb;
    }
    __syncthreads();
    if (q == 0) {
        float a = redp[0][h][0] + redp[1][h][0] + redp[2][h][0] + redp[3][h][0];
        float bb = redp[0][h][1] + redp[1][h][1] + redp[2][h][1] + redp[3][h][1];
        Ei[n * Hh + h] = __expf(-(a + ba1[h]));
        EjT[h * Nn + n] = __expf(-bb);
    }
}

// ---------------- phase B: coeffs + row-GEMM, 4 rows x FULL j per block ----
// Grid = 256, 1024 threads. Thread owns ONE j; one EjT vector load per k
// feeds all 4 rows. Ei/Wa2 read with wave-uniform indices -> s_load path.
// sm layout (floats): C @0 (4x1024), red @4096 (8x4x96=3072) = 28.7 KB.
__global__ __launch_bounds__(1024) void attn_kernel_u0(
    const float* __restrict__ Ei, const float* __restrict__ EjT,
    const float* __restrict__ Wa2, const float* __restrict__ ba2,
    const int* __restrict__ adj, const float* __restrict__ xB,
    float* __restrict__ xOut)
{
    __shared__ float sm[7168];
    int tid = threadIdx.x;
    int i0 = blockIdx.x * 4;
    {
        int j = tid;
        int m0 = adj[(i0 + 0) * Nn + j];
        int m1 = adj[(i0 + 1) * Nn + j];
        int m2 = adj[(i0 + 2) * Nn + j];
        int m3 = adj[(i0 + 3) * Nn + j];
        const float* e0 = Ei + i0 * Hh;       // uniform base
        float s0 = 0.f, s1 = 0.f, s2 = 0.f, s3 = 0.f;
#pragma unroll 8
        for (int k = 0; k < Hh; ++k) {
            float e = EjT[k * Nn + j];
            float wk = Wa2[k];                 // s_load
            s0 += __builtin_amdgcn_rcpf(fmaf(e0[k], e, 1.0f)) * wk;
            s1 += __builtin_amdgcn_rcpf(fmaf(e0[96 + k], e, 1.0f)) * wk;
            s2 += __builtin_amdgcn_rcpf(fmaf(e0[192 + k], e, 1.0f)) * wk;
            s3 += __builtin_amdgcn_rcpf(fmaf(e0[288 + k], e, 1.0f)) * wk;
        }
        float b2 = ba2[0];
        sm[0 * Nn + j] = (m0 == 1) ? sigf(s0 + b2) : 0.0f;
        sm[1 * Nn + j] = (m1 == 1) ? sigf(s1 + b2) : 0.0f;
        sm[2 * Nn + j] = (m2 == 1) ? sigf(s2 + b2) : 0.0f;
        sm[3 * Nn + j] = (m3 == 1) ? sigf(s3 + b2) : 0.0f;
    }
    __syncthreads();
    {
        int q = tid >> 7;
        int h = tid & 127;
        if (h < Hh) {
            int jb = q * 128;
            const float* xc = xB + jb * XS + h;
            const float* c0 = sm + 0 * Nn + jb;
            const float* c1 = sm + 1 * Nn + jb;
            const float* c2 = sm + 2 * Nn + jb;
            const float* c3 = sm + 3 * Nn + jb;
            float a0 = 0.f, a1 = 0.f, a2 = 0.f, a3 = 0.f;
#pragma unroll 4
            for (int j = 0; j < 128; ++j) {
                float xv = xc[j * XS];
                a0 += c0[j] * xv;
                a1 += c1[j] * xv;
                a2 += c2[j] * xv;
                a3 += c3[j] * xv;
            }
            sm[4096 + ((q * 4 + 0) * Hh) + h] = a0;
            sm[4096 + ((q * 4 + 1) * Hh) + h] = a1;
            sm[4096 + ((q * 4 + 2) * Hh) + h] = a2;
            sm[4096 + ((q * 4 + 3) * Hh) + h] = a3;
        }
    }
    __syncthreads();
    if (tid < 4 * Hh) {
        int r = tid / Hh, h = tid - r * Hh;
        float v = 0.f;
#pragma unroll
        for (int q = 0; q < 8; ++q)
            v += sm[4096 + ((q * 4 + r) * Hh) + h];
        xOut[(i0 + r) * XS + h] = v;
    }
}

__global__ __launch_bounds__(1024) void attn_kernel_u1(
    const float* __restrict__ Ei, const float* __restrict__ EjT,
    const float* __restrict__ Wa2, const float* __restrict__ ba2,
    const int* __restrict__ adj, const float* __restrict__ xB,
    const float* __restrict__ Wt_o1, const float* __restrict__ bo1,
    const float* __restrict__ Wt_o2, const float* __restrict__ bo2,
    const float* __restrict__ Wp1, const float* __restrict__ bp1,
    const float* __restrict__ Wp2, const float* __restrict__ bp2,
    float* __restrict__ out)
{
    __shared__ float sm[7168];
    __shared__ float hd[3][4][Hh];    // xout, t1, t2 for the fused head
    int tid = threadIdx.x;
    int i0 = blockIdx.x * 4;
    {
        int j = tid;
        int m0 = adj[(i0 + 0) * Nn + j];
        int m1 = adj[(i0 + 1) * Nn + j];
        int m2 = adj[(i0 + 2) * Nn + j];
        int m3 = adj[(i0 + 3) * Nn + j];
        const float* e0 = Ei + i0 * Hh;
        float s0 = 0.f, s1 = 0.f, s2 = 0.f, s3 = 0.f;
#pragma unroll 8
        for (int k = 0; k < Hh; ++k) {
            float e = EjT[k * Nn + j];
            float wk = Wa2[k];
            s0 += __builtin_amdgcn_rcpf(fmaf(e0[k], e, 1.0f)) * wk;
            s1 += __builtin_amdgcn_rcpf(fmaf(e0[96 + k], e, 1.0f)) * wk;
            s2 += __builtin_amdgcn_rcpf(fmaf(e0[192 + k], e, 1.0f)) * wk;
            s3 += __builtin_amdgcn_rcpf(fmaf(e0[288 + k], e, 1.0f)) * wk;
        }
        float b2 = ba2[0];
        sm[0 * Nn + j] = (m0 == 1) ? sigf(s0 + b2) : 0.0f;
        sm[1 * Nn + j] = (m1 == 1) ? sigf(s1 + b2) : 0.0f;
        sm[2 * Nn + j] = (m2 == 1) ? sigf(s2 + b2) : 0.0f;
        sm[3 * Nn + j] = (m3 == 1) ? sigf(s3 + b2) : 0.0f;
    }
    __syncthreads();
    {
        int q = tid >> 7;
        int h = tid & 127;
        if (h < Hh) {
            int jb = q * 128;
            const float* xc = xB + jb * XS + h;
            const float* c0 = sm + 0 * Nn + jb;
            const float* c1 = sm + 1 * Nn + jb;
            const float* c2 = sm + 2 * Nn + jb;
            const float* c3 = sm + 3 * Nn + jb;
            float a0 = 0.f, a1 = 0.f, a2 = 0.f, a3 = 0.f;
#pragma unroll 4
            for (int j = 0; j < 128; ++j) {
                float xv = xc[j * XS];
                a0 += c0[j] * xv;
                a1 += c1[j] * xv;
                a2 += c2[j] * xv;
                a3 += c3[j] * xv;
            }
            sm[4096 + ((q * 4 + 0) * Hh) + h] = a0;
            sm[4096 + ((q * 4 + 1) * Hh) + h] = a1;
            sm[4096 + ((q * 4 + 2) * Hh) + h] = a2;
            sm[4096 + ((q * 4 + 3) * Hh) + h] = a3;
        }
    }
    __syncthreads();
    if (tid < 4 * Hh) {
        int r = tid / Hh, h = tid - r * Hh;
        float v = 0.f;
#pragma unroll
        for (int q = 0; q < 8; ++q)
            v += sm[4096 + ((q * 4 + r) * Hh) + h];
        hd[0][r][h] = v;
    }
    __syncthreads();
    if (tid < 4 * Hh) {
        int r = tid / Hh, h = tid - r * Hh;
        const float* w = Wt_o1 + h;
        const float* xr = hd[0][r];
        float acc = bo1[h];
        for (int k = 0; k < Hh; ++k) acc += xr[k] * w[k * 96];
        hd[1][r][h] = leakyf(acc);
    }
    __syncthreads();
    if (tid < 4 * Hh) {
        int r = tid / Hh, h = tid - r * Hh;
        const float* w = Wt_o2 + h;
        const float* xr = hd[1][r];
        float acc = bo2[h];
        for (int k = 0; k < Hh; ++k) acc += xr[k] * w[k * 96];
        hd[2][r][h] = leakyf(acc);
    }
    __syncthreads();
    if (tid < 8) {
        int r = tid >> 1, which = tid & 1;
        const float* wp = which ? Wp2 : Wp1;
        const float* xr = hd[2][r];
        float acc = 0.f;
        for (int k = 0; k < Hh; ++k) acc += xr[k] * wp[k];
        float b = which ? bp2[0] : bp1[0];
        out[which * Nn + i0 + r] = sigf(acc + b);
    }
}

extern "C" void kernel_launch(void* const* d_in, const int* in_sizes, int n_in,
                              void* d_out, int out_size, void* d_ws, size_t ws_size,
                              hipStream_t stream)
{
    const float* x_in   = (const float*)d_in[0];
    const int*   ei     = (const int*)d_in[1];
    const int*   adj    = (const int*)d_in[2];
    const float* W_init = (const float*)d_in[3];
    const float* b_init = (const float*)d_in[4];
    const float* W_ggc  = (const float*)d_in[5];
    const float* W_ih   = (const float*)d_in[6];
    const float* W_hh   = (const float*)d_in[7];
    const float* b_ih   = (const float*)d_in[8];
    const float* b_hh   = (const float*)d_in[9];
    const float* Wa1    = (const float*)d_in[10];
    const float* ba1    = (const float*)d_in[11];
    const float* Wa2    = (const float*)d_in[12];
    const float* ba2    = (const float*)d_in[13];
    const float* Wo1    = (const float*)d_in[14];
    const float* bo1    = (const float*)d_in[15];
    const float* Wo2    = (const float*)d_in[16];
    const float* bo2    = (const float*)d_in[17];
    const float* Wp1    = (const float*)d_in[18];
    const float* bp1    = (const float*)d_in[19];
    const float* Wp2    = (const float*)d_in[20];
    const float* bp2    = (const float*)d_in[21];
    float* out = (float*)d_out;

    // workspace layout, ~2.5 MB
    float* ws     = (float*)d_ws;
    float* xA     = ws;                     // (N, XS)
    float* xB     = xA + Nn * XS;           // (N, XS)
    float* xC     = xB + Nn * XS;           // (N, XS)
    float* Ei     = xC + Nn * XS;           // (N, 96)
    float* EjT    = Ei + NH;                // (96, N)
    float* Wt_hh  = EjT + NH;               // 96*288
    float* Wf     = Wt_hh + 27648;          // 96*288
    float* Wt_a1i = Wf + 27648;             // 96*96
    float* Wt_a1j = Wt_a1i + 9216;
    float* Wt_o1  = Wt_a1j + 9216;
    float* Wt_o2  = Wt_o1 + 9216;
    int*   deg    = (int*)(Wt_o2 + 9216);   // (N)
    int*   bucket = deg + Nn;               // (N, SLOTS)

    setup_kernel<<<(NH + 255) / 256, 256, 0, stream>>>(
        W_hh, Wa1, Wo1, Wo2, W_ggc, W_ih, x_in, W_init, b_init,
        Wt_hh, Wt_a1i, Wt_a1j, Wt_o1, Wt_o2, Wf, deg, xA);
    edges_kernel<<<(Ee + 255) / 256, 256, 0, stream>>>(ei, deg, bucket);

    // unroll 0: xA -> xB -> xC
    gru_kernel<<<Nn, 384, 0, stream>>>(
        xA, deg, bucket, Wf, Wt_hh, b_ih, b_hh, Wt_a1i, Wt_a1j, ba1,
        xB, Ei, EjT);
    attn_kernel_u0<<<Nn / 4, 1024, 0, stream>>>(
        Ei, EjT, Wa2, ba2, adj, xB, xC);
    // unroll 1: xC -> xB -> (head fused) -> out
    gru_kernel<<<Nn, 384, 0, stream>>>(
        xC, deg, bucket, Wf, Wt_hh, b_ih, b_hh, Wt_a1i, Wt_a1j, ba1,
        xB, Ei, EjT);
    attn_kernel_u1<<<Nn / 4, 1024, 0, stream>>>(
        Ei, EjT, Wa2, ba2, adj, xB,
        Wt_o1, bo1, Wt_o2, bo2, Wp1, bp1, Wp2, bp2, out);
}